// Round 4
// baseline (1193.996 us; speedup 1.0000x reference)
//
#include <hip/hip_runtime.h>

#define N_NODES 50000
#define F_IN 256
#define F_H 128
#define F_OUT 64
#define E_MAX 1600000
#define NEG_SLOPE 0.2f
#define EPS_F 1e-16f
#define NPART 196              // ceil(50000/256)

// ---------------- device-global scratch ------------------------------------
__device__ float g_Wl1t[F_H * F_IN];    // transposed [n][k]
__device__ float g_Wr1t[F_H * F_IN];
__device__ float g_Wl2t[F_OUT * F_H];
__device__ float g_Wr2t[F_OUT * F_H];
__device__ float g_xl1[(size_t)N_NODES * F_H];
__device__ float g_xr1[(size_t)N_NODES * F_H];
__device__ float g_h[(size_t)N_NODES * F_H];      // layer-1 out (relu'd)
__device__ float g_xl2[(size_t)N_NODES * F_OUT];
__device__ float g_xr2[(size_t)N_NODES * F_OUT];
// CSR by dst
__device__ unsigned g_cnt[N_NODES];
__device__ unsigned g_part[NPART];
__device__ unsigned g_rowstart[N_NODES + 1];
__device__ unsigned g_cursor[N_NODES];
__device__ int g_src_sorted[E_MAX];

// ---------------- helpers ---------------------------------------------------
__device__ inline float san(float v) { return fminf(fmaxf(v, -64.f), 64.f); }

// ---------------- weight transpose (sanitized) ------------------------------
__global__ void wconv_all(const float* __restrict__ Wl1,
                          const float* __restrict__ Wr1,
                          const float* __restrict__ Wl2,
                          const float* __restrict__ Wr2) {
    int i = blockIdx.x * blockDim.x + threadIdx.x;
    if (i < F_IN * F_H) {
        int k = i / F_H, n = i % F_H;
        g_Wl1t[n * F_IN + k] = san(Wl1[i]);
        g_Wr1t[n * F_IN + k] = san(Wr1[i]);
    }
    if (i < F_H * F_OUT) {
        int k = i / F_OUT, n = i % F_OUT;
        g_Wl2t[n * F_H + k] = san(Wl2[i]);
        g_Wr2t[n * F_H + k] = san(Wr2[i]);
    }
}

// ---------------- CSR build --------------------------------------------------
__global__ void csr_zero() {
    int i = blockIdx.x * blockDim.x + threadIdx.x;
    if (i < N_NODES) g_cnt[i] = 0u;
}
__global__ void csr_hist(const int* __restrict__ dst, int E) {
    int e = blockIdx.x * blockDim.x + threadIdx.x;
    if (e < E) atomicAdd(&g_cnt[dst[e]], 1u);
}
// parallel 3-kernel exclusive scan
__global__ __launch_bounds__(256) void scanA() {
    int i = blockIdx.x * 256 + threadIdx.x;
    unsigned v = (i < N_NODES) ? g_cnt[i] : 0u;
#pragma unroll
    for (int off = 32; off > 0; off >>= 1) v += __shfl_xor(v, off, 64);
    __shared__ unsigned ws[4];
    if ((threadIdx.x & 63) == 0) ws[threadIdx.x >> 6] = v;
    __syncthreads();
    if (threadIdx.x == 0) g_part[blockIdx.x] = ws[0] + ws[1] + ws[2] + ws[3];
}
__global__ __launch_bounds__(256) void scanB(int E) {
    __shared__ unsigned lds[256];
    int t = threadIdx.x;
    unsigned v = (t < NPART) ? g_part[t] : 0u;
    lds[t] = v;
    __syncthreads();
    for (int off = 1; off < 256; off <<= 1) {
        unsigned u = (t >= off) ? lds[t - off] : 0u;
        __syncthreads();
        lds[t] += u;
        __syncthreads();
    }
    if (t < NPART) g_part[t] = lds[t] - v;      // exclusive block offsets
    if (t == 0) g_rowstart[N_NODES] = (unsigned)E;
}
__global__ __launch_bounds__(256) void scanC() {
    __shared__ unsigned lds[256];
    int t = threadIdx.x;
    int i = blockIdx.x * 256 + t;
    unsigned v = (i < N_NODES) ? g_cnt[i] : 0u;
    lds[t] = v;
    __syncthreads();
    for (int off = 1; off < 256; off <<= 1) {
        unsigned u = (t >= off) ? lds[t - off] : 0u;
        __syncthreads();
        lds[t] += u;
        __syncthreads();
    }
    unsigned excl = lds[t] - v + g_part[blockIdx.x];
    if (i < N_NODES) { g_rowstart[i] = excl; g_cursor[i] = excl; }
}
__global__ void csr_scatter(const int* __restrict__ src,
                            const int* __restrict__ dst, int E) {
    int e = blockIdx.x * blockDim.x + threadIdx.x;
    if (e >= E) return;
    unsigned pos = atomicAdd(&g_cursor[dst[e]], 1u);
    g_src_sorted[pos] = src[e];
}

// ---------------- GEMM 1: xl1/xr1 = x @ Wl1 / x @ Wr1  (M=50000,K=256,N=128)
__global__ __launch_bounds__(256) void gemm1(const float* __restrict__ x) {
    __shared__ float As[32 * F_IN];              // 32 KiB
    int m0 = blockIdx.x * 32;
    int tid = threadIdx.x;
    for (int i = tid; i < 32 * (F_IN / 4); i += 256) {
        int r = i >> 6;
        int k4 = i & 63;
        int m = m0 + r;
        float4 a = make_float4(0.f, 0.f, 0.f, 0.f);
        if (m < N_NODES) a = ((const float4*)(x + (size_t)m * F_IN))[k4];
        a.x = san(a.x); a.y = san(a.y); a.z = san(a.z); a.w = san(a.w);
        ((float4*)As)[i] = a;
    }
    __syncthreads();
    int c = tid & 127;
    int hh = tid >> 7;
    const float* __restrict__ bl = g_Wl1t + c * F_IN;
    const float* __restrict__ br = g_Wr1t + c * F_IN;
    float accl[16], accr[16];
#pragma unroll
    for (int r = 0; r < 16; ++r) { accl[r] = 0.f; accr[r] = 0.f; }
    for (int k = 0; k < F_IN; k += 4) {
        float4 vl = *(const float4*)(bl + k);
        float4 vr = *(const float4*)(br + k);
#pragma unroll
        for (int r = 0; r < 16; ++r) {
            float4 a = *(const float4*)(&As[(hh * 16 + r) * F_IN + k]);
            accl[r] = fmaf(a.x, vl.x, accl[r]);
            accl[r] = fmaf(a.y, vl.y, accl[r]);
            accl[r] = fmaf(a.z, vl.z, accl[r]);
            accl[r] = fmaf(a.w, vl.w, accl[r]);
            accr[r] = fmaf(a.x, vr.x, accr[r]);
            accr[r] = fmaf(a.y, vr.y, accr[r]);
            accr[r] = fmaf(a.z, vr.z, accr[r]);
            accr[r] = fmaf(a.w, vr.w, accr[r]);
        }
    }
#pragma unroll
    for (int r = 0; r < 16; ++r) {
        int m = m0 + hh * 16 + r;
        if (m < N_NODES) {
            g_xl1[(size_t)m * F_H + c] = accl[r];
            g_xr1[(size_t)m * F_H + c] = accr[r];
        }
    }
}

// ---------------- GEMM 2: xl2/xr2 = h @ Wl2 / h @ Wr2  (M=50000,K=128,N=64)
__global__ __launch_bounds__(128) void gemm2() {
    __shared__ float As[32 * F_H];
    int m0 = blockIdx.x * 32;
    int tid = threadIdx.x;
    for (int i = tid; i < 32 * (F_H / 4); i += 128) {
        int r = i >> 5;
        int k4 = i & 31;
        int m = m0 + r;
        float4 a = make_float4(0.f, 0.f, 0.f, 0.f);
        if (m < N_NODES) a = ((const float4*)(g_h + (size_t)m * F_H))[k4];
        ((float4*)As)[i] = a;
    }
    __syncthreads();
    int c = tid & 63;
    int hh = tid >> 6;
    const float* __restrict__ bl = g_Wl2t + c * F_H;
    const float* __restrict__ br = g_Wr2t + c * F_H;
    float accl[16], accr[16];
#pragma unroll
    for (int r = 0; r < 16; ++r) { accl[r] = 0.f; accr[r] = 0.f; }
    for (int k = 0; k < F_H; k += 4) {
        float4 vl = *(const float4*)(bl + k);
        float4 vr = *(const float4*)(br + k);
#pragma unroll
        for (int r = 0; r < 16; ++r) {
            float4 a = *(const float4*)(&As[(hh * 16 + r) * F_H + k]);
            accl[r] = fmaf(a.x, vl.x, accl[r]);
            accl[r] = fmaf(a.y, vl.y, accl[r]);
            accl[r] = fmaf(a.z, vl.z, accl[r]);
            accl[r] = fmaf(a.w, vl.w, accl[r]);
            accr[r] = fmaf(a.x, vr.x, accr[r]);
            accr[r] = fmaf(a.y, vr.y, accr[r]);
            accr[r] = fmaf(a.z, vr.z, accr[r]);
            accr[r] = fmaf(a.w, vr.w, accr[r]);
        }
    }
#pragma unroll
    for (int r = 0; r < 16; ++r) {
        int m = m0 + hh * 16 + r;
        if (m < N_NODES) {
            g_xl2[(size_t)m * F_OUT + c] = accl[r];
            g_xr2[(size_t)m * F_OUT + c] = accr[r];
        }
    }
}

// ---------------- fused softmax+aggregate, layer 1 (one wave per dst) -------
// Phase A: lane i computes the FULL logit of edge i (edge-parallel, no
// per-edge reductions). One max/exp/sum reduction per 64-edge chunk.
// Phase B: per-edge serial accumulate: shfl + float2 load + 2 FMA only.
__global__ __launch_bounds__(256) void sm_agg1(const float* __restrict__ att,
                                               const float* __restrict__ bias) {
    __shared__ float s_att[F_H];
    __shared__ float s_xr[4][F_H];
    int wid = threadIdx.x >> 6;
    int lane = threadIdx.x & 63;
    int w = blockIdx.x * 4 + wid;                 // dst node (50000 % 4 == 0)
    if (threadIdx.x < F_H) s_att[threadIdx.x] = san(att[threadIdx.x]);
    __syncthreads();
    int f2 = lane * 2;
    float2 xrv = *(const float2*)(g_xr1 + (size_t)w * F_H + f2);
    *(float2*)(&s_xr[wid][f2]) = xrv;             // same-wave RAW: no barrier
    int beg = (int)g_rowstart[w], end = (int)g_rowstart[w + 1];
    float m = -INFINITY, ssum = 0.f;
    float2 acc = make_float2(0.f, 0.f);
    for (int b0 = beg; b0 < end; b0 += 64) {
        int n = min(64, end - b0);
        int mysrc = (lane < n) ? g_src_sorted[b0 + lane] : 0;
        float e = -INFINITY;
        if (lane < n) {
            const float* __restrict__ xlrow = g_xl1 + (size_t)mysrc * F_H;
            float a0 = 0.f, a1 = 0.f;
#pragma unroll
            for (int f = 0; f < F_H; f += 4) {
                float4 xl4 = *(const float4*)(xlrow + f);
                float4 xr4 = *(const float4*)(&s_xr[wid][f]);
                float4 at4 = *(const float4*)(&s_att[f]);
                float z0 = xl4.x + xr4.x; z0 = z0 >= 0.f ? z0 : NEG_SLOPE * z0;
                float z1 = xl4.y + xr4.y; z1 = z1 >= 0.f ? z1 : NEG_SLOPE * z1;
                float z2 = xl4.z + xr4.z; z2 = z2 >= 0.f ? z2 : NEG_SLOPE * z2;
                float z3 = xl4.w + xr4.w; z3 = z3 >= 0.f ? z3 : NEG_SLOPE * z3;
                a0 = fmaf(z0, at4.x, a0);
                a1 = fmaf(z1, at4.y, a1);
                a0 = fmaf(z2, at4.z, a0);
                a1 = fmaf(z3, at4.w, a1);
            }
            e = a0 + a1;
        }
        float mc = e;
#pragma unroll
        for (int off = 32; off > 0; off >>= 1) mc = fmaxf(mc, __shfl_xor(mc, off, 64));
        float mn = fmaxf(m, mc);                  // mc finite (n>=1)
        float p = __expf(e - mn);                 // idle lanes: exp(-inf)=0
        float psum = p;
#pragma unroll
        for (int off = 32; off > 0; off >>= 1) psum += __shfl_xor(psum, off, 64);
        float scale = __expf(m - mn);             // first chunk: exp(-inf)=0
        ssum = ssum * scale + psum;
        acc.x *= scale; acc.y *= scale;
        m = mn;
        for (int j = 0; j < n; ++j) {
            int s = __shfl(mysrc, j, 64);
            float pj = __shfl(p, j, 64);
            float2 xl = *(const float2*)(g_xl1 + (size_t)s * F_H + f2);
            acc.x = fmaf(pj, xl.x, acc.x);
            acc.y = fmaf(pj, xl.y, acc.y);
        }
    }
    float inv = 1.f / (ssum + EPS_F);
    float o0 = acc.x * inv + san(bias[f2]);
    float o1 = acc.y * inv + san(bias[f2 + 1]);
    o0 = o0 > 0.f ? o0 : 0.f;
    o1 = o1 > 0.f ? o1 : 0.f;
    *(float2*)(g_h + (size_t)w * F_H + f2) = make_float2(o0, o1);
}

// ---------------- fused softmax+aggregate, layer 2 (F=64) -------------------
__global__ __launch_bounds__(256) void sm_agg2(const float* __restrict__ att,
                                               const float* __restrict__ bias,
                                               float* __restrict__ out) {
    __shared__ float s_att[F_OUT];
    __shared__ float s_xr[4][F_OUT];
    int wid = threadIdx.x >> 6;
    int lane = threadIdx.x & 63;
    int w = blockIdx.x * 4 + wid;
    if (threadIdx.x < F_OUT) s_att[threadIdx.x] = san(att[threadIdx.x]);
    __syncthreads();
    float xrv = g_xr2[(size_t)w * F_OUT + lane];
    s_xr[wid][lane] = xrv;
    int beg = (int)g_rowstart[w], end = (int)g_rowstart[w + 1];
    float m = -INFINITY, ssum = 0.f, acc = 0.f;
    for (int b0 = beg; b0 < end; b0 += 64) {
        int n = min(64, end - b0);
        int mysrc = (lane < n) ? g_src_sorted[b0 + lane] : 0;
        float e = -INFINITY;
        if (lane < n) {
            const float* __restrict__ xlrow = g_xl2 + (size_t)mysrc * F_OUT;
            float a0 = 0.f, a1 = 0.f;
#pragma unroll
            for (int f = 0; f < F_OUT; f += 4) {
                float4 xl4 = *(const float4*)(xlrow + f);
                float4 xr4 = *(const float4*)(&s_xr[wid][f]);
                float4 at4 = *(const float4*)(&s_att[f]);
                float z0 = xl4.x + xr4.x; z0 = z0 >= 0.f ? z0 : NEG_SLOPE * z0;
                float z1 = xl4.y + xr4.y; z1 = z1 >= 0.f ? z1 : NEG_SLOPE * z1;
                float z2 = xl4.z + xr4.z; z2 = z2 >= 0.f ? z2 : NEG_SLOPE * z2;
                float z3 = xl4.w + xr4.w; z3 = z3 >= 0.f ? z3 : NEG_SLOPE * z3;
                a0 = fmaf(z0, at4.x, a0);
                a1 = fmaf(z1, at4.y, a1);
                a0 = fmaf(z2, at4.z, a0);
                a1 = fmaf(z3, at4.w, a1);
            }
            e = a0 + a1;
        }
        float mc = e;
#pragma unroll
        for (int off = 32; off > 0; off >>= 1) mc = fmaxf(mc, __shfl_xor(mc, off, 64));
        float mn = fmaxf(m, mc);
        float p = __expf(e - mn);
        float psum = p;
#pragma unroll
        for (int off = 32; off > 0; off >>= 1) psum += __shfl_xor(psum, off, 64);
        float scale = __expf(m - mn);
        ssum = ssum * scale + psum;
        acc *= scale;
        m = mn;
        for (int j = 0; j < n; ++j) {
            int s = __shfl(mysrc, j, 64);
            float pj = __shfl(p, j, 64);
            acc = fmaf(pj, g_xl2[(size_t)s * F_OUT + lane], acc);
        }
    }
    out[(size_t)w * F_OUT + lane] = acc / (ssum + EPS_F) + san(bias[lane]);
}

// ---------------- launch ------------------------------------------------------
extern "C" void kernel_launch(void* const* d_in, const int* in_sizes, int n_in,
                              void* d_out, int out_size, void* d_ws, size_t ws_size,
                              hipStream_t stream) {
    const float* x    = (const float*)d_in[0];
    const int*   ei   = (const int*)d_in[1];
    const float* Wl1  = (const float*)d_in[2];
    const float* Wr1  = (const float*)d_in[3];
    const float* att1 = (const float*)d_in[4];
    const float* b1   = (const float*)d_in[5];
    const float* Wl2  = (const float*)d_in[6];
    const float* Wr2  = (const float*)d_in[7];
    const float* att2 = (const float*)d_in[8];
    const float* b2   = (const float*)d_in[9];

    int E = in_sizes[1] / 2;
    const int* src = ei;
    const int* dst = ei + E;

    int gM = (N_NODES + 31) / 32;
    int gE = (E + 255) / 256;
    int gN = N_NODES / 4;                        // 4 dst-waves per block

    wconv_all<<<(F_IN * F_H + 255) / 256, 256, 0, stream>>>(Wl1, Wr1, Wl2, Wr2);

    // CSR by dst
    csr_zero<<<NPART, 256, 0, stream>>>();
    csr_hist<<<gE, 256, 0, stream>>>(dst, E);
    scanA<<<NPART, 256, 0, stream>>>();
    scanB<<<1, 256, 0, stream>>>(E);
    scanC<<<NPART, 256, 0, stream>>>();
    csr_scatter<<<gE, 256, 0, stream>>>(src, dst, E);

    // ---- layer 1 ----
    gemm1<<<gM, 256, 0, stream>>>(x);
    sm_agg1<<<gN, 256, 0, stream>>>(att1, b1);

    // ---- layer 2 ----
    gemm2<<<gM, 128, 0, stream>>>();
    sm_agg2<<<gN, 256, 0, stream>>>(att2, b2, (float*)d_out);
}

// Round 5
// 684.095 us; speedup vs baseline: 1.7454x; 1.7454x over previous
//
#include <hip/hip_runtime.h>

#define N_NODES 50000
#define F_IN 256
#define F_H 128
#define F_OUT 64
#define E_MAX 1600000
#define NEG_SLOPE 0.2f
#define EPS_F 1e-16f
#define NPART 196              // ceil(50000/256)

// ---------------- device-global scratch ------------------------------------
__device__ float g_Wl1t[F_H * F_IN];    // transposed [n][k]
__device__ float g_Wr1t[F_H * F_IN];
__device__ float g_Wl2t[F_OUT * F_H];
__device__ float g_Wr2t[F_OUT * F_H];
__device__ float g_xl1[(size_t)N_NODES * F_H];
__device__ float g_xr1[(size_t)N_NODES * F_H];
__device__ float g_h[(size_t)N_NODES * F_H];      // layer-1 out (relu'd)
__device__ float g_xl2[(size_t)N_NODES * F_OUT];
__device__ float g_xr2[(size_t)N_NODES * F_OUT];
// CSR by dst
__device__ unsigned g_cnt[N_NODES];
__device__ unsigned g_part[NPART];
__device__ unsigned g_rowstart[N_NODES + 1];
__device__ unsigned g_cursor[N_NODES];
__device__ int g_src_sorted[E_MAX];

// ---------------- helpers ---------------------------------------------------
__device__ inline float san(float v) { return fminf(fmaxf(v, -64.f), 64.f); }
__device__ inline float lrelu(float z) { return fmaxf(z, NEG_SLOPE * z); }

// ---------------- weight transpose (sanitized) ------------------------------
__global__ void wconv_all(const float* __restrict__ Wl1,
                          const float* __restrict__ Wr1,
                          const float* __restrict__ Wl2,
                          const float* __restrict__ Wr2) {
    int i = blockIdx.x * blockDim.x + threadIdx.x;
    if (i < F_IN * F_H) {
        int k = i / F_H, n = i % F_H;
        g_Wl1t[n * F_IN + k] = san(Wl1[i]);
        g_Wr1t[n * F_IN + k] = san(Wr1[i]);
    }
    if (i < F_H * F_OUT) {
        int k = i / F_OUT, n = i % F_OUT;
        g_Wl2t[n * F_H + k] = san(Wl2[i]);
        g_Wr2t[n * F_H + k] = san(Wr2[i]);
    }
}

// ---------------- CSR build --------------------------------------------------
__global__ void csr_zero() {
    int i = blockIdx.x * blockDim.x + threadIdx.x;
    if (i < N_NODES) g_cnt[i] = 0u;
}
__global__ void csr_hist(const int* __restrict__ dst, int E) {
    int e = blockIdx.x * blockDim.x + threadIdx.x;
    if (e < E) atomicAdd(&g_cnt[dst[e]], 1u);
}
__global__ __launch_bounds__(256) void scanA() {
    int i = blockIdx.x * 256 + threadIdx.x;
    unsigned v = (i < N_NODES) ? g_cnt[i] : 0u;
#pragma unroll
    for (int off = 32; off > 0; off >>= 1) v += __shfl_xor(v, off, 64);
    __shared__ unsigned ws[4];
    if ((threadIdx.x & 63) == 0) ws[threadIdx.x >> 6] = v;
    __syncthreads();
    if (threadIdx.x == 0) g_part[blockIdx.x] = ws[0] + ws[1] + ws[2] + ws[3];
}
__global__ __launch_bounds__(256) void scanB(int E) {
    __shared__ unsigned lds[256];
    int t = threadIdx.x;
    unsigned v = (t < NPART) ? g_part[t] : 0u;
    lds[t] = v;
    __syncthreads();
    for (int off = 1; off < 256; off <<= 1) {
        unsigned u = (t >= off) ? lds[t - off] : 0u;
        __syncthreads();
        lds[t] += u;
        __syncthreads();
    }
    if (t < NPART) g_part[t] = lds[t] - v;
    if (t == 0) g_rowstart[N_NODES] = (unsigned)E;
}
__global__ __launch_bounds__(256) void scanC() {
    __shared__ unsigned lds[256];
    int t = threadIdx.x;
    int i = blockIdx.x * 256 + t;
    unsigned v = (i < N_NODES) ? g_cnt[i] : 0u;
    lds[t] = v;
    __syncthreads();
    for (int off = 1; off < 256; off <<= 1) {
        unsigned u = (t >= off) ? lds[t - off] : 0u;
        __syncthreads();
        lds[t] += u;
        __syncthreads();
    }
    unsigned excl = lds[t] - v + g_part[blockIdx.x];
    if (i < N_NODES) { g_rowstart[i] = excl; g_cursor[i] = excl; }
}
__global__ void csr_scatter(const int* __restrict__ src,
                            const int* __restrict__ dst, int E) {
    int e = blockIdx.x * blockDim.x + threadIdx.x;
    if (e >= E) return;
    unsigned pos = atomicAdd(&g_cursor[dst[e]], 1u);
    g_src_sorted[pos] = src[e];
}

// ---------------- GEMM 1: xl1/xr1 = x @ Wl1 / x @ Wr1  (M=50000,K=256,N=128)
__global__ __launch_bounds__(256) void gemm1(const float* __restrict__ x) {
    __shared__ float As[32 * F_IN];
    int m0 = blockIdx.x * 32;
    int tid = threadIdx.x;
    for (int i = tid; i < 32 * (F_IN / 4); i += 256) {
        int r = i >> 6;
        int k4 = i & 63;
        int m = m0 + r;
        float4 a = make_float4(0.f, 0.f, 0.f, 0.f);
        if (m < N_NODES) a = ((const float4*)(x + (size_t)m * F_IN))[k4];
        a.x = san(a.x); a.y = san(a.y); a.z = san(a.z); a.w = san(a.w);
        ((float4*)As)[i] = a;
    }
    __syncthreads();
    int c = tid & 127;
    int hh = tid >> 7;
    const float* __restrict__ bl = g_Wl1t + c * F_IN;
    const float* __restrict__ br = g_Wr1t + c * F_IN;
    float accl[16], accr[16];
#pragma unroll
    for (int r = 0; r < 16; ++r) { accl[r] = 0.f; accr[r] = 0.f; }
    for (int k = 0; k < F_IN; k += 4) {
        float4 vl = *(const float4*)(bl + k);
        float4 vr = *(const float4*)(br + k);
#pragma unroll
        for (int r = 0; r < 16; ++r) {
            float4 a = *(const float4*)(&As[(hh * 16 + r) * F_IN + k]);
            accl[r] = fmaf(a.x, vl.x, accl[r]);
            accl[r] = fmaf(a.y, vl.y, accl[r]);
            accl[r] = fmaf(a.z, vl.z, accl[r]);
            accl[r] = fmaf(a.w, vl.w, accl[r]);
            accr[r] = fmaf(a.x, vr.x, accr[r]);
            accr[r] = fmaf(a.y, vr.y, accr[r]);
            accr[r] = fmaf(a.z, vr.z, accr[r]);
            accr[r] = fmaf(a.w, vr.w, accr[r]);
        }
    }
#pragma unroll
    for (int r = 0; r < 16; ++r) {
        int m = m0 + hh * 16 + r;
        if (m < N_NODES) {
            g_xl1[(size_t)m * F_H + c] = accl[r];
            g_xr1[(size_t)m * F_H + c] = accr[r];
        }
    }
}

// ---------------- GEMM 2: xl2/xr2 = h @ Wl2 / h @ Wr2  (M=50000,K=128,N=64)
__global__ __launch_bounds__(128) void gemm2() {
    __shared__ float As[32 * F_H];
    int m0 = blockIdx.x * 32;
    int tid = threadIdx.x;
    for (int i = tid; i < 32 * (F_H / 4); i += 128) {
        int r = i >> 5;
        int k4 = i & 31;
        int m = m0 + r;
        float4 a = make_float4(0.f, 0.f, 0.f, 0.f);
        if (m < N_NODES) a = ((const float4*)(g_h + (size_t)m * F_H))[k4];
        ((float4*)As)[i] = a;
    }
    __syncthreads();
    int c = tid & 63;
    int hh = tid >> 6;
    const float* __restrict__ bl = g_Wl2t + c * F_H;
    const float* __restrict__ br = g_Wr2t + c * F_H;
    float accl[16], accr[16];
#pragma unroll
    for (int r = 0; r < 16; ++r) { accl[r] = 0.f; accr[r] = 0.f; }
    for (int k = 0; k < F_H; k += 4) {
        float4 vl = *(const float4*)(bl + k);
        float4 vr = *(const float4*)(br + k);
#pragma unroll
        for (int r = 0; r < 16; ++r) {
            float4 a = *(const float4*)(&As[(hh * 16 + r) * F_H + k]);
            accl[r] = fmaf(a.x, vl.x, accl[r]);
            accl[r] = fmaf(a.y, vl.y, accl[r]);
            accl[r] = fmaf(a.z, vl.z, accl[r]);
            accl[r] = fmaf(a.w, vl.w, accl[r]);
            accr[r] = fmaf(a.x, vr.x, accr[r]);
            accr[r] = fmaf(a.y, vr.y, accr[r]);
            accr[r] = fmaf(a.z, vr.z, accr[r]);
            accr[r] = fmaf(a.w, vr.w, accr[r]);
        }
    }
#pragma unroll
    for (int r = 0; r < 16; ++r) {
        int m = m0 + hh * 16 + r;
        if (m < N_NODES) {
            g_xl2[(size_t)m * F_OUT + c] = accl[r];
            g_xr2[(size_t)m * F_OUT + c] = accr[r];
        }
    }
}

// ---------------- fused attention+aggregate, layer 1 ------------------------
// One wave per dst. 8 edges/round x 8 lanes/edge x 16 features/lane.
// Each xl row is loaded ONCE (coalesced dwordx4), kept in regs for both the
// logit dot and the p-weighted accumulate. 6 shfl stages per 8 edges.
__global__ __launch_bounds__(256) void att_agg1(const float* __restrict__ att,
                                                const float* __restrict__ bias) {
    __shared__ float s_out[4][F_H];
    int wid = threadIdx.x >> 6, lane = threadIdx.x & 63;
    int w = blockIdx.x * 4 + wid;                 // dst node (grid exact)
    int g = lane >> 3;                            // edge group 0..7
    int fi = lane & 7;                            // feature slice 0..7
    int f0 = fi * 16;

    float4 xr[4], at[4];
    const float4* xrp = (const float4*)(g_xr1 + (size_t)w * F_H + f0);
    const float4* atp = (const float4*)(att + f0);
#pragma unroll
    for (int q = 0; q < 4; ++q) {
        xr[q] = xrp[q];
        float4 a = atp[q];
        a.x = san(a.x); a.y = san(a.y); a.z = san(a.z); a.w = san(a.w);
        at[q] = a;
    }

    int beg = (int)g_rowstart[w], end = (int)g_rowstart[w + 1];
    float m = -INFINITY, ssum = 0.f;
    float4 acc[4];
#pragma unroll
    for (int q = 0; q < 4; ++q) acc[q] = make_float4(0.f, 0.f, 0.f, 0.f);

    for (int c0 = beg; c0 < end; c0 += 64) {
        int nc = min(64, end - c0);
        int mysrc = (lane < nc) ? g_src_sorted[c0 + lane] : 0;
        for (int r0 = 0; r0 < nc; r0 += 8) {
            int eidx = r0 + g;
            bool valid = eidx < nc;
            int s = __shfl(mysrc, eidx, 64);     // 0 if invalid (guarded)
            const float4* rowp = (const float4*)(g_xl1 + (size_t)s * F_H + f0);
            float4 row[4];
#pragma unroll
            for (int q = 0; q < 4; ++q) row[q] = rowp[q];
            float d = 0.f;
#pragma unroll
            for (int q = 0; q < 4; ++q) {
                float z;
                z = row[q].x + xr[q].x; d = fmaf(lrelu(z), at[q].x, d);
                z = row[q].y + xr[q].y; d = fmaf(lrelu(z), at[q].y, d);
                z = row[q].z + xr[q].z; d = fmaf(lrelu(z), at[q].z, d);
                z = row[q].w + xr[q].w; d = fmaf(lrelu(z), at[q].w, d);
            }
            d += __shfl_xor(d, 1, 64);           // combine 8-lane group dot
            d += __shfl_xor(d, 2, 64);
            d += __shfl_xor(d, 4, 64);
            float e = valid ? d : -INFINITY;
            float M = e;                          // round max over 8 edges
            M = fmaxf(M, __shfl_xor(M, 8, 64));
            M = fmaxf(M, __shfl_xor(M, 16, 64));
            M = fmaxf(M, __shfl_xor(M, 32, 64));
            float mn = fmaxf(m, M);               // finite: >=1 valid edge
            float sc = __expf(m - mn);            // 0 on first round
            float p  = __expf(e - mn);            // 0 for invalid edges
            m = mn;
            ssum = ssum * sc + p;
#pragma unroll
            for (int q = 0; q < 4; ++q) {
                acc[q].x = fmaf(p, row[q].x, acc[q].x * sc);
                acc[q].y = fmaf(p, row[q].y, acc[q].y * sc);
                acc[q].z = fmaf(p, row[q].z, acc[q].z * sc);
                acc[q].w = fmaf(p, row[q].w, acc[q].w * sc);
            }
        }
    }
    // cross-group reduction (each edge lives in exactly one group)
#pragma unroll
    for (int off = 8; off < 64; off <<= 1) {
        ssum += __shfl_xor(ssum, off, 64);
#pragma unroll
        for (int q = 0; q < 4; ++q) {
            acc[q].x += __shfl_xor(acc[q].x, off, 64);
            acc[q].y += __shfl_xor(acc[q].y, off, 64);
            acc[q].z += __shfl_xor(acc[q].z, off, 64);
            acc[q].w += __shfl_xor(acc[q].w, off, 64);
        }
    }
    float inv = 1.f / (ssum + EPS_F);
    if (g == 0) {
        float4* op = (float4*)&s_out[wid][f0];
#pragma unroll
        for (int q = 0; q < 4; ++q) {
            float4 v;
            v.x = acc[q].x * inv; v.y = acc[q].y * inv;
            v.z = acc[q].z * inv; v.w = acc[q].w * inv;
            op[q] = v;
        }
    }
    __syncthreads();
    int f2 = lane * 2;
    float2 o = *(float2*)&s_out[wid][f2];
    o.x = fmaxf(o.x + san(bias[f2]), 0.f);        // bias + relu
    o.y = fmaxf(o.y + san(bias[f2 + 1]), 0.f);
    *(float2*)(g_h + (size_t)w * F_H + f2) = o;
}

// ---------------- fused attention+aggregate, layer 2 (F=64) -----------------
// Same structure: 8 edges/round x 8 lanes/edge x 8 features/lane.
__global__ __launch_bounds__(256) void att_agg2(const float* __restrict__ att,
                                                const float* __restrict__ bias,
                                                float* __restrict__ out) {
    __shared__ float s_out[4][F_OUT];
    int wid = threadIdx.x >> 6, lane = threadIdx.x & 63;
    int w = blockIdx.x * 4 + wid;
    int g = lane >> 3;
    int fi = lane & 7;
    int f0 = fi * 8;

    float4 xr[2], at[2];
    const float4* xrp = (const float4*)(g_xr2 + (size_t)w * F_OUT + f0);
    const float4* atp = (const float4*)(att + f0);
#pragma unroll
    for (int q = 0; q < 2; ++q) {
        xr[q] = xrp[q];
        float4 a = atp[q];
        a.x = san(a.x); a.y = san(a.y); a.z = san(a.z); a.w = san(a.w);
        at[q] = a;
    }

    int beg = (int)g_rowstart[w], end = (int)g_rowstart[w + 1];
    float m = -INFINITY, ssum = 0.f;
    float4 acc[2];
#pragma unroll
    for (int q = 0; q < 2; ++q) acc[q] = make_float4(0.f, 0.f, 0.f, 0.f);

    for (int c0 = beg; c0 < end; c0 += 64) {
        int nc = min(64, end - c0);
        int mysrc = (lane < nc) ? g_src_sorted[c0 + lane] : 0;
        for (int r0 = 0; r0 < nc; r0 += 8) {
            int eidx = r0 + g;
            bool valid = eidx < nc;
            int s = __shfl(mysrc, eidx, 64);
            const float4* rowp = (const float4*)(g_xl2 + (size_t)s * F_OUT + f0);
            float4 row[2];
#pragma unroll
            for (int q = 0; q < 2; ++q) row[q] = rowp[q];
            float d = 0.f;
#pragma unroll
            for (int q = 0; q < 2; ++q) {
                float z;
                z = row[q].x + xr[q].x; d = fmaf(lrelu(z), at[q].x, d);
                z = row[q].y + xr[q].y; d = fmaf(lrelu(z), at[q].y, d);
                z = row[q].z + xr[q].z; d = fmaf(lrelu(z), at[q].z, d);
                z = row[q].w + xr[q].w; d = fmaf(lrelu(z), at[q].w, d);
            }
            d += __shfl_xor(d, 1, 64);
            d += __shfl_xor(d, 2, 64);
            d += __shfl_xor(d, 4, 64);
            float e = valid ? d : -INFINITY;
            float M = e;
            M = fmaxf(M, __shfl_xor(M, 8, 64));
            M = fmaxf(M, __shfl_xor(M, 16, 64));
            M = fmaxf(M, __shfl_xor(M, 32, 64));
            float mn = fmaxf(m, M);
            float sc = __expf(m - mn);
            float p  = __expf(e - mn);
            m = mn;
            ssum = ssum * sc + p;
#pragma unroll
            for (int q = 0; q < 2; ++q) {
                acc[q].x = fmaf(p, row[q].x, acc[q].x * sc);
                acc[q].y = fmaf(p, row[q].y, acc[q].y * sc);
                acc[q].z = fmaf(p, row[q].z, acc[q].z * sc);
                acc[q].w = fmaf(p, row[q].w, acc[q].w * sc);
            }
        }
    }
#pragma unroll
    for (int off = 8; off < 64; off <<= 1) {
        ssum += __shfl_xor(ssum, off, 64);
#pragma unroll
        for (int q = 0; q < 2; ++q) {
            acc[q].x += __shfl_xor(acc[q].x, off, 64);
            acc[q].y += __shfl_xor(acc[q].y, off, 64);
            acc[q].z += __shfl_xor(acc[q].z, off, 64);
            acc[q].w += __shfl_xor(acc[q].w, off, 64);
        }
    }
    float inv = 1.f / (ssum + EPS_F);
    if (g == 0) {
        float4* op = (float4*)&s_out[wid][f0];
#pragma unroll
        for (int q = 0; q < 2; ++q) {
            float4 v;
            v.x = acc[q].x * inv; v.y = acc[q].y * inv;
            v.z = acc[q].z * inv; v.w = acc[q].w * inv;
            op[q] = v;
        }
    }
    __syncthreads();
    out[(size_t)w * F_OUT + lane] = s_out[wid][lane] + san(bias[lane]);
}

// ---------------- launch ------------------------------------------------------
extern "C" void kernel_launch(void* const* d_in, const int* in_sizes, int n_in,
                              void* d_out, int out_size, void* d_ws, size_t ws_size,
                              hipStream_t stream) {
    const float* x    = (const float*)d_in[0];
    const int*   ei   = (const int*)d_in[1];
    const float* Wl1  = (const float*)d_in[2];
    const float* Wr1  = (const float*)d_in[3];
    const float* att1 = (const float*)d_in[4];
    const float* b1   = (const float*)d_in[5];
    const float* Wl2  = (const float*)d_in[6];
    const float* Wr2  = (const float*)d_in[7];
    const float* att2 = (const float*)d_in[8];
    const float* b2   = (const float*)d_in[9];

    int E = in_sizes[1] / 2;
    const int* src = ei;
    const int* dst = ei + E;

    int gM = (N_NODES + 31) / 32;
    int gE = (E + 255) / 256;
    int gN = N_NODES / 4;                        // 4 dst-waves per block

    wconv_all<<<(F_IN * F_H + 255) / 256, 256, 0, stream>>>(Wl1, Wr1, Wl2, Wr2);

    // CSR by dst
    csr_zero<<<NPART, 256, 0, stream>>>();
    csr_hist<<<gE, 256, 0, stream>>>(dst, E);
    scanA<<<NPART, 256, 0, stream>>>();
    scanB<<<1, 256, 0, stream>>>(E);
    scanC<<<NPART, 256, 0, stream>>>();
    csr_scatter<<<gE, 256, 0, stream>>>(src, dst, E);

    // ---- layer 1 ----
    gemm1<<<gM, 256, 0, stream>>>(x);
    att_agg1<<<gN, 256, 0, stream>>>(att1, b1);

    // ---- layer 2 ----
    gemm2<<<gM, 128, 0, stream>>>();
    att_agg2<<<gN, 256, 0, stream>>>(att2, b2, (float*)d_out);
}

// Round 6
// 588.386 us; speedup vs baseline: 2.0293x; 1.1627x over previous
//
#include <hip/hip_runtime.h>

#define N_NODES 50000
#define M_PAD 50048            // 391 * 128
#define MT 391
#define F_IN 256
#define F_H 128
#define F_OUT 64
#define E_MAX 1600000
#define NEG_SLOPE 0.2f
#define EPS_F 1e-16f
#define NPART 196              // ceil(50000/256)

typedef __bf16 bf16x8 __attribute__((ext_vector_type(8)));
typedef float f32x4 __attribute__((ext_vector_type(4)));

// ---------------- device-global scratch ------------------------------------
// B matrices prepacked [n][k] (transposed), bf16 hi/lo
__device__ unsigned short g_B1h[256 * 256];
__device__ unsigned short g_B1l[256 * 256];
__device__ unsigned short g_B2h[128 * 128];
__device__ unsigned short g_B2l[128 * 128];
// A matrices bf16 hi/lo, M padded to 50048 (pad rows zeroed)
__device__ unsigned short g_x1h[(size_t)M_PAD * F_IN];
__device__ unsigned short g_x1l[(size_t)M_PAD * F_IN];
__device__ unsigned short g_hh[(size_t)M_PAD * F_H];
__device__ unsigned short g_hl[(size_t)M_PAD * F_H];
// GEMM outputs fp32
__device__ float g_xl1[(size_t)N_NODES * F_H];
__device__ float g_xr1[(size_t)N_NODES * F_H];
__device__ float g_xl2[(size_t)N_NODES * F_OUT];
__device__ float g_xr2[(size_t)N_NODES * F_OUT];
// CSR by dst
__device__ unsigned g_cnt[N_NODES];
__device__ unsigned g_part[NPART];
__device__ unsigned g_rowstart[N_NODES + 1];
__device__ unsigned g_cursor[N_NODES];
__device__ int g_src_sorted[E_MAX];

// ---------------- helpers ---------------------------------------------------
__device__ inline float san(float v) { return fminf(fmaxf(v, -64.f), 64.f); }
__device__ inline float lrelu(float z) { return fmaxf(z, NEG_SLOPE * z); }
__device__ inline unsigned short f2bf(float f) {        // RNE f32->bf16
    unsigned u = __float_as_uint(f);
    return (unsigned short)((u + 0x7fffu + ((u >> 16) & 1u)) >> 16);
}
__device__ inline float bf2f(unsigned short h) {
    return __uint_as_float(((unsigned)h) << 16);
}

// ---------------- weight prepack: [k][n] f32 -> [n][k] bf16 hi/lo -----------
__global__ void wconv_all(const float* __restrict__ Wl1,
                          const float* __restrict__ Wr1,
                          const float* __restrict__ Wl2,
                          const float* __restrict__ Wr2) {
    int i = blockIdx.x * blockDim.x + threadIdx.x;
    if (i < 256 * 256) {                       // layer 1: N=256 (Wl|Wr), K=256
        int n = i >> 8, k = i & 255;
        float v = san((n < 128) ? Wl1[k * 128 + n] : Wr1[k * 128 + (n - 128)]);
        unsigned short h = f2bf(v);
        g_B1h[n * 256 + k] = h;
        g_B1l[n * 256 + k] = f2bf(v - bf2f(h));
    }
    if (i < 128 * 128) {                       // layer 2: N=128 (Wl|Wr), K=128
        int n = i >> 7, k = i & 127;
        float v = san((n < 64) ? Wl2[k * 64 + n] : Wr2[k * 64 + (n - 64)]);
        unsigned short h = f2bf(v);
        g_B2h[n * 128 + k] = h;
        g_B2l[n * 128 + k] = f2bf(v - bf2f(h));
    }
}

// ---------------- x split: f32 [50000][256] -> bf16 hi/lo [50048][256] ------
__global__ void split_x(const float* __restrict__ x) {
    int i = blockIdx.x * 256 + threadIdx.x;       // per float4; grid exact
    int m = i >> 6, c4 = i & 63;
    float4 v = make_float4(0.f, 0.f, 0.f, 0.f);
    if (m < N_NODES) v = ((const float4*)(x + (size_t)m * F_IN))[c4];
    v.x = san(v.x); v.y = san(v.y); v.z = san(v.z); v.w = san(v.w);
    unsigned short h0 = f2bf(v.x), h1 = f2bf(v.y), h2 = f2bf(v.z), h3 = f2bf(v.w);
    unsigned short l0 = f2bf(v.x - bf2f(h0)), l1 = f2bf(v.y - bf2f(h1));
    unsigned short l2 = f2bf(v.z - bf2f(h2)), l3 = f2bf(v.w - bf2f(h3));
    size_t o = (size_t)m * F_IN + c4 * 4;
    uint2 ph = make_uint2(((unsigned)h1 << 16) | h0, ((unsigned)h3 << 16) | h2);
    uint2 pl = make_uint2(((unsigned)l1 << 16) | l0, ((unsigned)l3 << 16) | l2);
    *(uint2*)(g_x1h + o) = ph;
    *(uint2*)(g_x1l + o) = pl;
}

// zero h pad rows (globals re-poisoned before every launch)
__global__ void pad_h() {
    int i = blockIdx.x * 256 + threadIdx.x;
    if (i < (M_PAD - N_NODES) * F_H) {
        g_hh[(size_t)N_NODES * F_H + i] = 0;
        g_hl[(size_t)N_NODES * F_H + i] = 0;
    }
}

// ---------------- CSR build --------------------------------------------------
__global__ void csr_zero() {
    int i = blockIdx.x * blockDim.x + threadIdx.x;
    if (i < N_NODES) g_cnt[i] = 0u;
}
__global__ void csr_hist(const int* __restrict__ dst, int E) {
    int e = blockIdx.x * blockDim.x + threadIdx.x;
    if (e < E) atomicAdd(&g_cnt[dst[e]], 1u);
}
__global__ __launch_bounds__(256) void scanA() {
    int i = blockIdx.x * 256 + threadIdx.x;
    unsigned v = (i < N_NODES) ? g_cnt[i] : 0u;
#pragma unroll
    for (int off = 32; off > 0; off >>= 1) v += __shfl_xor(v, off, 64);
    __shared__ unsigned ws[4];
    if ((threadIdx.x & 63) == 0) ws[threadIdx.x >> 6] = v;
    __syncthreads();
    if (threadIdx.x == 0) g_part[blockIdx.x] = ws[0] + ws[1] + ws[2] + ws[3];
}
__global__ __launch_bounds__(256) void scanB(int E) {
    __shared__ unsigned lds[256];
    int t = threadIdx.x;
    unsigned v = (t < NPART) ? g_part[t] : 0u;
    lds[t] = v;
    __syncthreads();
    for (int off = 1; off < 256; off <<= 1) {
        unsigned u = (t >= off) ? lds[t - off] : 0u;
        __syncthreads();
        lds[t] += u;
        __syncthreads();
    }
    if (t < NPART) g_part[t] = lds[t] - v;
    if (t == 0) g_rowstart[N_NODES] = (unsigned)E;
}
__global__ __launch_bounds__(256) void scanC() {
    __shared__ unsigned lds[256];
    int t = threadIdx.x;
    int i = blockIdx.x * 256 + t;
    unsigned v = (i < N_NODES) ? g_cnt[i] : 0u;
    lds[t] = v;
    __syncthreads();
    for (int off = 1; off < 256; off <<= 1) {
        unsigned u = (t >= off) ? lds[t - off] : 0u;
        __syncthreads();
        lds[t] += u;
        __syncthreads();
    }
    unsigned excl = lds[t] - v + g_part[blockIdx.x];
    if (i < N_NODES) { g_rowstart[i] = excl; g_cursor[i] = excl; }
}
__global__ void csr_scatter(const int* __restrict__ src,
                            const int* __restrict__ dst, int E) {
    int e = blockIdx.x * blockDim.x + threadIdx.x;
    if (e >= E) return;
    unsigned pos = atomicAdd(&g_cursor[dst[e]], 1u);
    g_src_sorted[pos] = src[e];
}

// ---------------- split-bf16 MFMA GEMM --------------------------------------
// C[M x Ntot] = A[M x K] * B[K x Ntot], A~(Ah+Al), B~(Bh+Bl), 3-term product.
// Block: 256 thr = 4 waves (2x2), tile 128x128, 16x16x32 bf16 MFMA.
// A staged [row][k] pitch 40, B staged [n][k] pitch 40 (B global is [n][k]).
template<int LAYER>
__global__ __launch_bounds__(256) void gemm_mfma() {
    constexpr int K    = (LAYER == 1) ? 256 : 128;
    constexpr int NSPL = (LAYER == 1) ? 128 : 64;   // col split: O1 | O2
    const unsigned short* __restrict__ Ah = (LAYER == 1) ? g_x1h : g_hh;
    const unsigned short* __restrict__ Al = (LAYER == 1) ? g_x1l : g_hl;
    const unsigned short* __restrict__ Bh = (LAYER == 1) ? g_B1h : g_B2h;
    const unsigned short* __restrict__ Bl = (LAYER == 1) ? g_B1l : g_B2l;
    float* __restrict__ O1 = (LAYER == 1) ? g_xl1 : g_xl2;
    float* __restrict__ O2 = (LAYER == 1) ? g_xr1 : g_xr2;

    __shared__ __align__(16) unsigned short As_h[128][40];
    __shared__ __align__(16) unsigned short As_l[128][40];
    __shared__ __align__(16) unsigned short Bs_h[128][40];
    __shared__ __align__(16) unsigned short Bs_l[128][40];

    const int m0 = blockIdx.x * 128;
    const int n0 = blockIdx.y * 128;
    const int t = threadIdx.x;
    const int wave = t >> 6, lane = t & 63;
    const int wm = (wave >> 1) * 64, wn = (wave & 1) * 64;
    const int lr = lane & 15, g8 = (lane >> 4) * 8;
    const int srow = t >> 1, shalf = (t & 1) * 16;   // staging: 2 thr/row, 32B each

    f32x4 acc[4][4];
#pragma unroll
    for (int i = 0; i < 4; ++i)
#pragma unroll
        for (int j = 0; j < 4; ++j) acc[i][j] = (f32x4){0.f, 0.f, 0.f, 0.f};

    for (int kb = 0; kb < K; kb += 32) {
        __syncthreads();
        {
            size_t ga = (size_t)(m0 + srow) * K + kb + shalf;
            *(uint4*)&As_h[srow][shalf]     = *(const uint4*)(Ah + ga);
            *(uint4*)&As_h[srow][shalf + 8] = *(const uint4*)(Ah + ga + 8);
            *(uint4*)&As_l[srow][shalf]     = *(const uint4*)(Al + ga);
            *(uint4*)&As_l[srow][shalf + 8] = *(const uint4*)(Al + ga + 8);
            size_t gb = (size_t)(n0 + srow) * K + kb + shalf;
            *(uint4*)&Bs_h[srow][shalf]     = *(const uint4*)(Bh + gb);
            *(uint4*)&Bs_h[srow][shalf + 8] = *(const uint4*)(Bh + gb + 8);
            *(uint4*)&Bs_l[srow][shalf]     = *(const uint4*)(Bl + gb);
            *(uint4*)&Bs_l[srow][shalf + 8] = *(const uint4*)(Bl + gb + 8);
        }
        __syncthreads();

        bf16x8 af_h[4], af_l[4], bf_h[4], bf_l[4];
#pragma unroll
        for (int i = 0; i < 4; ++i) {
            af_h[i] = *(const bf16x8*)&As_h[wm + i * 16 + lr][g8];
            af_l[i] = *(const bf16x8*)&As_l[wm + i * 16 + lr][g8];
        }
#pragma unroll
        for (int j = 0; j < 4; ++j) {
            bf_h[j] = *(const bf16x8*)&Bs_h[wn + j * 16 + lr][g8];
            bf_l[j] = *(const bf16x8*)&Bs_l[wn + j * 16 + lr][g8];
        }
#pragma unroll
        for (int i = 0; i < 4; ++i)
#pragma unroll
            for (int j = 0; j < 4; ++j) {
                acc[i][j] = __builtin_amdgcn_mfma_f32_16x16x32_bf16(af_h[i], bf_h[j], acc[i][j], 0, 0, 0);
                acc[i][j] = __builtin_amdgcn_mfma_f32_16x16x32_bf16(af_h[i], bf_l[j], acc[i][j], 0, 0, 0);
                acc[i][j] = __builtin_amdgcn_mfma_f32_16x16x32_bf16(af_l[i], bf_h[j], acc[i][j], 0, 0, 0);
            }
    }

    // epilogue: C/D layout col=lane&15, row=(lane>>4)*4+reg
    const int drow = (lane >> 4) * 4;
#pragma unroll
    for (int i = 0; i < 4; ++i)
#pragma unroll
        for (int j = 0; j < 4; ++j) {
            int gn = n0 + wn + j * 16 + lr;
            float* Optr = (gn < NSPL) ? O1 : O2;
            int col = (gn < NSPL) ? gn : gn - NSPL;
#pragma unroll
            for (int r = 0; r < 4; ++r) {
                int m = m0 + wm + i * 16 + drow + r;
                if (m < N_NODES) Optr[(size_t)m * NSPL + col] = acc[i][j][r];
            }
        }
}

// ---------------- fused attention+aggregate, layer 1 ------------------------
// One wave per dst. 8 edges/round x 8 lanes/edge x 16 features/lane.
__global__ __launch_bounds__(256) void att_agg1(const float* __restrict__ att,
                                                const float* __restrict__ bias) {
    __shared__ float s_out[4][F_H];
    int wid = threadIdx.x >> 6, lane = threadIdx.x & 63;
    int w = blockIdx.x * 4 + wid;
    int g = lane >> 3;
    int fi = lane & 7;
    int f0 = fi * 16;

    float4 xr[4], at[4];
    const float4* xrp = (const float4*)(g_xr1 + (size_t)w * F_H + f0);
    const float4* atp = (const float4*)(att + f0);
#pragma unroll
    for (int q = 0; q < 4; ++q) {
        xr[q] = xrp[q];
        float4 a = atp[q];
        a.x = san(a.x); a.y = san(a.y); a.z = san(a.z); a.w = san(a.w);
        at[q] = a;
    }

    int beg = (int)g_rowstart[w], end = (int)g_rowstart[w + 1];
    float m = -INFINITY, ssum = 0.f;
    float4 acc[4];
#pragma unroll
    for (int q = 0; q < 4; ++q) acc[q] = make_float4(0.f, 0.f, 0.f, 0.f);

    for (int c0 = beg; c0 < end; c0 += 64) {
        int nc = min(64, end - c0);
        int mysrc = (lane < nc) ? g_src_sorted[c0 + lane] : 0;
        for (int r0 = 0; r0 < nc; r0 += 8) {
            int eidx = r0 + g;
            bool valid = eidx < nc;
            int s = __shfl(mysrc, eidx, 64);
            const float4* rowp = (const float4*)(g_xl1 + (size_t)s * F_H + f0);
            float4 row[4];
#pragma unroll
            for (int q = 0; q < 4; ++q) row[q] = rowp[q];
            float d = 0.f;
#pragma unroll
            for (int q = 0; q < 4; ++q) {
                float z;
                z = row[q].x + xr[q].x; d = fmaf(lrelu(z), at[q].x, d);
                z = row[q].y + xr[q].y; d = fmaf(lrelu(z), at[q].y, d);
                z = row[q].z + xr[q].z; d = fmaf(lrelu(z), at[q].z, d);
                z = row[q].w + xr[q].w; d = fmaf(lrelu(z), at[q].w, d);
            }
            d += __shfl_xor(d, 1, 64);
            d += __shfl_xor(d, 2, 64);
            d += __shfl_xor(d, 4, 64);
            float e = valid ? d : -INFINITY;
            float M = e;
            M = fmaxf(M, __shfl_xor(M, 8, 64));
            M = fmaxf(M, __shfl_xor(M, 16, 64));
            M = fmaxf(M, __shfl_xor(M, 32, 64));
            float mn = fmaxf(m, M);
            float sc = __expf(m - mn);
            float p  = __expf(e - mn);
            m = mn;
            ssum = ssum * sc + p;
#pragma unroll
            for (int q = 0; q < 4; ++q) {
                acc[q].x = fmaf(p, row[q].x, acc[q].x * sc);
                acc[q].y = fmaf(p, row[q].y, acc[q].y * sc);
                acc[q].z = fmaf(p, row[q].z, acc[q].z * sc);
                acc[q].w = fmaf(p, row[q].w, acc[q].w * sc);
            }
        }
    }
#pragma unroll
    for (int off = 8; off < 64; off <<= 1) {
        ssum += __shfl_xor(ssum, off, 64);
#pragma unroll
        for (int q = 0; q < 4; ++q) {
            acc[q].x += __shfl_xor(acc[q].x, off, 64);
            acc[q].y += __shfl_xor(acc[q].y, off, 64);
            acc[q].z += __shfl_xor(acc[q].z, off, 64);
            acc[q].w += __shfl_xor(acc[q].w, off, 64);
        }
    }
    float inv = 1.f / (ssum + EPS_F);
    if (g == 0) {
        float4* op = (float4*)&s_out[wid][f0];
#pragma unroll
        for (int q = 0; q < 4; ++q) {
            float4 v;
            v.x = acc[q].x * inv; v.y = acc[q].y * inv;
            v.z = acc[q].z * inv; v.w = acc[q].w * inv;
            op[q] = v;
        }
    }
    __syncthreads();
    int f2 = lane * 2;
    float2 o = *(float2*)&s_out[wid][f2];
    o.x = fmaxf(o.x + san(bias[f2]), 0.f);       // bias + relu
    o.y = fmaxf(o.y + san(bias[f2 + 1]), 0.f);
    // emit h as bf16 hi/lo for the layer-2 MFMA GEMM
    unsigned short hx = f2bf(o.x), hy = f2bf(o.y);
    unsigned short lx = f2bf(o.x - bf2f(hx)), ly = f2bf(o.y - bf2f(hy));
    size_t base = (size_t)w * F_H + f2;
    *(unsigned*)(g_hh + base) = ((unsigned)hy << 16) | hx;
    *(unsigned*)(g_hl + base) = ((unsigned)ly << 16) | lx;
}

// ---------------- fused attention+aggregate, layer 2 (F=64) -----------------
__global__ __launch_bounds__(256) void att_agg2(const float* __restrict__ att,
                                                const float* __restrict__ bias,
                                                float* __restrict__ out) {
    __shared__ float s_out[4][F_OUT];
    int wid = threadIdx.x >> 6, lane = threadIdx.x & 63;
    int w = blockIdx.x * 4 + wid;
    int g = lane >> 3;
    int fi = lane & 7;
    int f0 = fi * 8;

    float4 xr[2], at[2];
    const float4* xrp = (const float4*)(g_xr2 + (size_t)w * F_OUT + f0);
    const float4* atp = (const float4*)(att + f0);
#pragma unroll
    for (int q = 0; q < 2; ++q) {
        xr[q] = xrp[q];
        float4 a = atp[q];
        a.x = san(a.x); a.y = san(a.y); a.z = san(a.z); a.w = san(a.w);
        at[q] = a;
    }

    int beg = (int)g_rowstart[w], end = (int)g_rowstart[w + 1];
    float m = -INFINITY, ssum = 0.f;
    float4 acc[2];
#pragma unroll
    for (int q = 0; q < 2; ++q) acc[q] = make_float4(0.f, 0.f, 0.f, 0.f);

    for (int c0 = beg; c0 < end; c0 += 64) {
        int nc = min(64, end - c0);
        int mysrc = (lane < nc) ? g_src_sorted[c0 + lane] : 0;
        for (int r0 = 0; r0 < nc; r0 += 8) {
            int eidx = r0 + g;
            bool valid = eidx < nc;
            int s = __shfl(mysrc, eidx, 64);
            const float4* rowp = (const float4*)(g_xl2 + (size_t)s * F_OUT + f0);
            float4 row[2];
#pragma unroll
            for (int q = 0; q < 2; ++q) row[q] = rowp[q];
            float d = 0.f;
#pragma unroll
            for (int q = 0; q < 2; ++q) {
                float z;
                z = row[q].x + xr[q].x; d = fmaf(lrelu(z), at[q].x, d);
                z = row[q].y + xr[q].y; d = fmaf(lrelu(z), at[q].y, d);
                z = row[q].z + xr[q].z; d = fmaf(lrelu(z), at[q].z, d);
                z = row[q].w + xr[q].w; d = fmaf(lrelu(z), at[q].w, d);
            }
            d += __shfl_xor(d, 1, 64);
            d += __shfl_xor(d, 2, 64);
            d += __shfl_xor(d, 4, 64);
            float e = valid ? d : -INFINITY;
            float M = e;
            M = fmaxf(M, __shfl_xor(M, 8, 64));
            M = fmaxf(M, __shfl_xor(M, 16, 64));
            M = fmaxf(M, __shfl_xor(M, 32, 64));
            float mn = fmaxf(m, M);
            float sc = __expf(m - mn);
            float p  = __expf(e - mn);
            m = mn;
            ssum = ssum * sc + p;
#pragma unroll
            for (int q = 0; q < 2; ++q) {
                acc[q].x = fmaf(p, row[q].x, acc[q].x * sc);
                acc[q].y = fmaf(p, row[q].y, acc[q].y * sc);
                acc[q].z = fmaf(p, row[q].z, acc[q].z * sc);
                acc[q].w = fmaf(p, row[q].w, acc[q].w * sc);
            }
        }
    }
#pragma unroll
    for (int off = 8; off < 64; off <<= 1) {
        ssum += __shfl_xor(ssum, off, 64);
#pragma unroll
        for (int q = 0; q < 2; ++q) {
            acc[q].x += __shfl_xor(acc[q].x, off, 64);
            acc[q].y += __shfl_xor(acc[q].y, off, 64);
            acc[q].z += __shfl_xor(acc[q].z, off, 64);
            acc[q].w += __shfl_xor(acc[q].w, off, 64);
        }
    }
    float inv = 1.f / (ssum + EPS_F);
    if (g == 0) {
        float4* op = (float4*)&s_out[wid][f0];
#pragma unroll
        for (int q = 0; q < 2; ++q) {
            float4 v;
            v.x = acc[q].x * inv; v.y = acc[q].y * inv;
            v.z = acc[q].z * inv; v.w = acc[q].w * inv;
            op[q] = v;
        }
    }
    __syncthreads();
    out[(size_t)w * F_OUT + lane] = s_out[wid][lane] + san(bias[lane]);
}

// ---------------- launch ------------------------------------------------------
extern "C" void kernel_launch(void* const* d_in, const int* in_sizes, int n_in,
                              void* d_out, int out_size, void* d_ws, size_t ws_size,
                              hipStream_t stream) {
    const float* x    = (const float*)d_in[0];
    const int*   ei   = (const int*)d_in[1];
    const float* Wl1  = (const float*)d_in[2];
    const float* Wr1  = (const float*)d_in[3];
    const float* att1 = (const float*)d_in[4];
    const float* b1   = (const float*)d_in[5];
    const float* Wl2  = (const float*)d_in[6];
    const float* Wr2  = (const float*)d_in[7];
    const float* att2 = (const float*)d_in[8];
    const float* b2   = (const float*)d_in[9];

    int E = in_sizes[1] / 2;
    const int* src = ei;
    const int* dst = ei + E;

    int gE = (E + 255) / 256;
    int gN = N_NODES / 4;                         // 4 dst-waves per block
    int gSX = (M_PAD * (F_IN / 4)) / 256;         // split_x grid (exact)

    wconv_all<<<256, 256, 0, stream>>>(Wl1, Wr1, Wl2, Wr2);
    split_x<<<gSX, 256, 0, stream>>>(x);

    // CSR by dst
    csr_zero<<<NPART, 256, 0, stream>>>();
    csr_hist<<<gE, 256, 0, stream>>>(dst, E);
    scanA<<<NPART, 256, 0, stream>>>();
    scanB<<<1, 256, 0, stream>>>(E);
    scanC<<<NPART, 256, 0, stream>>>();
    csr_scatter<<<gE, 256, 0, stream>>>(src, dst, E);

    // ---- layer 1 ----
    gemm_mfma<1><<<dim3(MT, 2), 256, 0, stream>>>();
    att_agg1<<<gN, 256, 0, stream>>>(att1, b1);

    // ---- layer 2 ----
    pad_h<<<24, 256, 0, stream>>>();
    gemm_mfma<2><<<dim3(MT, 1), 256, 0, stream>>>();
    att_agg2<<<gN, 256, 0, stream>>>(att2, b2, (float*)d_out);
}

// Round 7
// 549.292 us; speedup vs baseline: 2.1737x; 1.0712x over previous
//
#include <hip/hip_runtime.h>

#define N_NODES 50000
#define M_PAD 50048            // 391 * 128
#define MT 391
#define F_IN 256
#define F_H 128
#define F_OUT 64
#define E_MAX 1600000
#define NEG_SLOPE 0.2f
#define EPS_F 1e-16f
#define NPART 196              // ceil(50000/256)
#define NBUCK 196              // coarse buckets: dst >> 8
#define CH_E 16384             // edges per sortA block

typedef __bf16 bf16x8 __attribute__((ext_vector_type(8)));
typedef float f32x4 __attribute__((ext_vector_type(4)));

// ---------------- device-global scratch ------------------------------------
__device__ unsigned short g_B1h[256 * 256];
__device__ unsigned short g_B1l[256 * 256];
__device__ unsigned short g_B2h[128 * 128];
__device__ unsigned short g_B2l[128 * 128];
__device__ unsigned short g_x1h[(size_t)M_PAD * F_IN];
__device__ unsigned short g_x1l[(size_t)M_PAD * F_IN];
__device__ unsigned short g_hh[(size_t)M_PAD * F_H];
__device__ unsigned short g_hl[(size_t)M_PAD * F_H];
__device__ float g_xl1[(size_t)N_NODES * F_H];
__device__ float g_xr1[(size_t)N_NODES * F_H];
__device__ float g_xl2[(size_t)N_NODES * F_OUT];
__device__ float g_xr2[(size_t)N_NODES * F_OUT];
// CSR by dst
__device__ unsigned g_cnt[N_NODES];
__device__ unsigned g_part[NPART];
__device__ unsigned g_rowstart[N_NODES + 1];
__device__ unsigned g_bcursor[NBUCK];
__device__ unsigned g_bucketed[E_MAX];     // packed src | dst<<16
__device__ int g_src_sorted[E_MAX];

// ---------------- helpers ---------------------------------------------------
__device__ inline float san(float v) { return fminf(fmaxf(v, -64.f), 64.f); }
__device__ inline float lrelu(float z) { return fmaxf(z, NEG_SLOPE * z); }
__device__ inline unsigned short f2bf(float f) {        // RNE f32->bf16
    unsigned u = __float_as_uint(f);
    return (unsigned short)((u + 0x7fffu + ((u >> 16) & 1u)) >> 16);
}
__device__ inline float bf2f(unsigned short h) {
    return __uint_as_float(((unsigned)h) << 16);
}

// ---------------- weight prepack: [k][n] f32 -> [n][k] bf16 hi/lo -----------
__global__ void wconv_all(const float* __restrict__ Wl1,
                          const float* __restrict__ Wr1,
                          const float* __restrict__ Wl2,
                          const float* __restrict__ Wr2) {
    int i = blockIdx.x * blockDim.x + threadIdx.x;
    if (i < 256 * 256) {
        int n = i >> 8, k = i & 255;
        float v = san((n < 128) ? Wl1[k * 128 + n] : Wr1[k * 128 + (n - 128)]);
        unsigned short h = f2bf(v);
        g_B1h[n * 256 + k] = h;
        g_B1l[n * 256 + k] = f2bf(v - bf2f(h));
    }
    if (i < 128 * 128) {
        int n = i >> 7, k = i & 127;
        float v = san((n < 64) ? Wl2[k * 64 + n] : Wr2[k * 64 + (n - 64)]);
        unsigned short h = f2bf(v);
        g_B2h[n * 128 + k] = h;
        g_B2l[n * 128 + k] = f2bf(v - bf2f(h));
    }
}

// ---------------- x split: f32 [50000][256] -> bf16 hi/lo [50048][256] ------
__global__ void split_x(const float* __restrict__ x) {
    int i = blockIdx.x * 256 + threadIdx.x;
    int m = i >> 6, c4 = i & 63;
    float4 v = make_float4(0.f, 0.f, 0.f, 0.f);
    if (m < N_NODES) v = ((const float4*)(x + (size_t)m * F_IN))[c4];
    v.x = san(v.x); v.y = san(v.y); v.z = san(v.z); v.w = san(v.w);
    unsigned short h0 = f2bf(v.x), h1 = f2bf(v.y), h2 = f2bf(v.z), h3 = f2bf(v.w);
    unsigned short l0 = f2bf(v.x - bf2f(h0)), l1 = f2bf(v.y - bf2f(h1));
    unsigned short l2 = f2bf(v.z - bf2f(h2)), l3 = f2bf(v.w - bf2f(h3));
    size_t o = (size_t)m * F_IN + c4 * 4;
    uint2 ph = make_uint2(((unsigned)h1 << 16) | h0, ((unsigned)h3 << 16) | h2);
    uint2 pl = make_uint2(((unsigned)l1 << 16) | l0, ((unsigned)l3 << 16) | l2);
    *(uint2*)(g_x1h + o) = ph;
    *(uint2*)(g_x1l + o) = pl;
}

__global__ void pad_h() {
    int i = blockIdx.x * 256 + threadIdx.x;
    if (i < (M_PAD - N_NODES) * F_H) {
        g_hh[(size_t)N_NODES * F_H + i] = 0;
        g_hl[(size_t)N_NODES * F_H + i] = 0;
    }
}

// ---------------- CSR build --------------------------------------------------
__global__ void csr_zero() {
    int i = blockIdx.x * blockDim.x + threadIdx.x;
    if (i < N_NODES) g_cnt[i] = 0u;
}
__global__ void csr_hist(const int* __restrict__ dst, int E) {
    int e = blockIdx.x * blockDim.x + threadIdx.x;
    if (e < E) atomicAdd(&g_cnt[dst[e]], 1u);
}
__global__ __launch_bounds__(256) void scanA() {
    int i = blockIdx.x * 256 + threadIdx.x;
    unsigned v = (i < N_NODES) ? g_cnt[i] : 0u;
#pragma unroll
    for (int off = 32; off > 0; off >>= 1) v += __shfl_xor(v, off, 64);
    __shared__ unsigned ws[4];
    if ((threadIdx.x & 63) == 0) ws[threadIdx.x >> 6] = v;
    __syncthreads();
    if (threadIdx.x == 0) g_part[blockIdx.x] = ws[0] + ws[1] + ws[2] + ws[3];
}
__global__ __launch_bounds__(256) void scanB(int E) {
    __shared__ unsigned lds[256];
    int t = threadIdx.x;
    unsigned v = (t < NPART) ? g_part[t] : 0u;
    lds[t] = v;
    __syncthreads();
    for (int off = 1; off < 256; off <<= 1) {
        unsigned u = (t >= off) ? lds[t - off] : 0u;
        __syncthreads();
        lds[t] += u;
        __syncthreads();
    }
    if (t < NPART) g_part[t] = lds[t] - v;
    if (t == 0) g_rowstart[N_NODES] = (unsigned)E;
}
__global__ __launch_bounds__(256) void scanC() {
    __shared__ unsigned lds[256];
    int t = threadIdx.x;
    int i = blockIdx.x * 256 + t;
    unsigned v = (i < N_NODES) ? g_cnt[i] : 0u;
    lds[t] = v;
    __syncthreads();
    for (int off = 1; off < 256; off <<= 1) {
        unsigned u = (t >= off) ? lds[t - off] : 0u;
        __syncthreads();
        lds[t] += u;
        __syncthreads();
    }
    if (i < N_NODES) g_rowstart[i] = lds[t] - v + g_part[blockIdx.x];
}
__global__ void binit() {
    int b = blockIdx.x * 256 + threadIdx.x;
    if (b < NBUCK) g_bcursor[b] = g_rowstart[min(b * 256, N_NODES)];
}

// ---------------- two-pass locality-aware sort ------------------------------
// Pass A: block-local bucket counts -> one cursor grab per (block,bucket) ->
// packed entries written into the block's contiguous sub-range per bucket.
__global__ __launch_bounds__(256) void sortA(const int* __restrict__ src,
                                             const int* __restrict__ dst, int E) {
    __shared__ unsigned l_cnt[NBUCK];
    __shared__ unsigned l_cur[NBUCK];
    __shared__ unsigned l_base[NBUCK];
    int t = threadIdx.x;
    int e0 = blockIdx.x * CH_E;
    int e1 = min(e0 + CH_E, E);
    for (int i = t; i < NBUCK; i += 256) { l_cnt[i] = 0u; l_cur[i] = 0u; }
    __syncthreads();
    for (int e = e0 + t; e < e1; e += 256)
        atomicAdd(&l_cnt[dst[e] >> 8], 1u);
    __syncthreads();
    for (int i = t; i < NBUCK; i += 256) {
        unsigned c = l_cnt[i];
        l_base[i] = c ? atomicAdd(&g_bcursor[i], c) : 0u;
    }
    __syncthreads();
    for (int e = e0 + t; e < e1; e += 256) {
        int d = dst[e];
        int b = d >> 8;
        unsigned off = atomicAdd(&l_cur[b], 1u);
        g_bucketed[l_base[b] + off] = (unsigned)src[e] | ((unsigned)d << 16);
    }
}
// Pass B: one block per bucket; fine positions from LDS cursors seeded with
// rowstart; writes stay inside the bucket's ~32 KB window (single XCD L2).
__global__ __launch_bounds__(256) void sortB() {
    __shared__ unsigned l_cur[256];
    int b = blockIdx.x;
    int d0 = b * 256;
    int t = threadIdx.x;
    l_cur[t] = g_rowstart[min(d0 + t, N_NODES)];
    unsigned bstart = g_rowstart[min(d0, N_NODES)];
    unsigned bend   = g_rowstart[min(d0 + 256, N_NODES)];
    __syncthreads();
    for (unsigned i = bstart + t; i < bend; i += 256) {
        unsigned e = g_bucketed[i];
        unsigned d = e >> 16;
        unsigned pos = atomicAdd(&l_cur[d - d0], 1u);
        g_src_sorted[pos] = (int)(e & 0xFFFFu);
    }
}

// ---------------- split-bf16 MFMA GEMM --------------------------------------
template<int LAYER>
__global__ __launch_bounds__(256) void gemm_mfma() {
    constexpr int K    = (LAYER == 1) ? 256 : 128;
    constexpr int NSPL = (LAYER == 1) ? 128 : 64;
    const unsigned short* __restrict__ Ah = (LAYER == 1) ? g_x1h : g_hh;
    const unsigned short* __restrict__ Al = (LAYER == 1) ? g_x1l : g_hl;
    const unsigned short* __restrict__ Bh = (LAYER == 1) ? g_B1h : g_B2h;
    const unsigned short* __restrict__ Bl = (LAYER == 1) ? g_B1l : g_B2l;
    float* __restrict__ O1 = (LAYER == 1) ? g_xl1 : g_xl2;
    float* __restrict__ O2 = (LAYER == 1) ? g_xr1 : g_xr2;

    __shared__ __align__(16) unsigned short As_h[128][40];
    __shared__ __align__(16) unsigned short As_l[128][40];
    __shared__ __align__(16) unsigned short Bs_h[128][40];
    __shared__ __align__(16) unsigned short Bs_l[128][40];

    const int m0 = blockIdx.x * 128;
    const int n0 = blockIdx.y * 128;
    const int t = threadIdx.x;
    const int wave = t >> 6, lane = t & 63;
    const int wm = (wave >> 1) * 64, wn = (wave & 1) * 64;
    const int lr = lane & 15, g8 = (lane >> 4) * 8;
    const int srow = t >> 1, shalf = (t & 1) * 16;

    f32x4 acc[4][4];
#pragma unroll
    for (int i = 0; i < 4; ++i)
#pragma unroll
        for (int j = 0; j < 4; ++j) acc[i][j] = (f32x4){0.f, 0.f, 0.f, 0.f};

    for (int kb = 0; kb < K; kb += 32) {
        __syncthreads();
        {
            size_t ga = (size_t)(m0 + srow) * K + kb + shalf;
            *(uint4*)&As_h[srow][shalf]     = *(const uint4*)(Ah + ga);
            *(uint4*)&As_h[srow][shalf + 8] = *(const uint4*)(Ah + ga + 8);
            *(uint4*)&As_l[srow][shalf]     = *(const uint4*)(Al + ga);
            *(uint4*)&As_l[srow][shalf + 8] = *(const uint4*)(Al + ga + 8);
            size_t gb = (size_t)(n0 + srow) * K + kb + shalf;
            *(uint4*)&Bs_h[srow][shalf]     = *(const uint4*)(Bh + gb);
            *(uint4*)&Bs_h[srow][shalf + 8] = *(const uint4*)(Bh + gb + 8);
            *(uint4*)&Bs_l[srow][shalf]     = *(const uint4*)(Bl + gb);
            *(uint4*)&Bs_l[srow][shalf + 8] = *(const uint4*)(Bl + gb + 8);
        }
        __syncthreads();

        bf16x8 af_h[4], af_l[4], bf_h[4], bf_l[4];
#pragma unroll
        for (int i = 0; i < 4; ++i) {
            af_h[i] = *(const bf16x8*)&As_h[wm + i * 16 + lr][g8];
            af_l[i] = *(const bf16x8*)&As_l[wm + i * 16 + lr][g8];
        }
#pragma unroll
        for (int j = 0; j < 4; ++j) {
            bf_h[j] = *(const bf16x8*)&Bs_h[wn + j * 16 + lr][g8];
            bf_l[j] = *(const bf16x8*)&Bs_l[wn + j * 16 + lr][g8];
        }
#pragma unroll
        for (int i = 0; i < 4; ++i)
#pragma unroll
            for (int j = 0; j < 4; ++j) {
                acc[i][j] = __builtin_amdgcn_mfma_f32_16x16x32_bf16(af_h[i], bf_h[j], acc[i][j], 0, 0, 0);
                acc[i][j] = __builtin_amdgcn_mfma_f32_16x16x32_bf16(af_h[i], bf_l[j], acc[i][j], 0, 0, 0);
                acc[i][j] = __builtin_amdgcn_mfma_f32_16x16x32_bf16(af_l[i], bf_h[j], acc[i][j], 0, 0, 0);
            }
    }

    const int drow = (lane >> 4) * 4;
#pragma unroll
    for (int i = 0; i < 4; ++i)
#pragma unroll
        for (int j = 0; j < 4; ++j) {
            int gn = n0 + wn + j * 16 + lr;
            float* Optr = (gn < NSPL) ? O1 : O2;
            int col = (gn < NSPL) ? gn : gn - NSPL;
#pragma unroll
            for (int r = 0; r < 4; ++r) {
                int m = m0 + wm + i * 16 + drow + r;
                if (m < N_NODES) Optr[(size_t)m * NSPL + col] = acc[i][j][r];
            }
        }
}

// ---------------- fused attention+aggregate, layer 1 ------------------------
__global__ __launch_bounds__(256) void att_agg1(const float* __restrict__ att,
                                                const float* __restrict__ bias) {
    __shared__ float s_out[4][F_H];
    int wid = threadIdx.x >> 6, lane = threadIdx.x & 63;
    int w = blockIdx.x * 4 + wid;
    int g = lane >> 3;
    int fi = lane & 7;
    int f0 = fi * 16;

    float4 xr[4], at[4];
    const float4* xrp = (const float4*)(g_xr1 + (size_t)w * F_H + f0);
    const float4* atp = (const float4*)(att + f0);
#pragma unroll
    for (int q = 0; q < 4; ++q) {
        xr[q] = xrp[q];
        float4 a = atp[q];
        a.x = san(a.x); a.y = san(a.y); a.z = san(a.z); a.w = san(a.w);
        at[q] = a;
    }

    int beg = (int)g_rowstart[w], end = (int)g_rowstart[w + 1];
    float m = -INFINITY, ssum = 0.f;
    float4 acc[4];
#pragma unroll
    for (int q = 0; q < 4; ++q) acc[q] = make_float4(0.f, 0.f, 0.f, 0.f);

    for (int c0 = beg; c0 < end; c0 += 64) {
        int nc = min(64, end - c0);
        int mysrc = (lane < nc) ? g_src_sorted[c0 + lane] : 0;
        for (int r0 = 0; r0 < nc; r0 += 8) {
            int eidx = r0 + g;
            bool valid = eidx < nc;
            int s = __shfl(mysrc, eidx, 64);
            const float4* rowp = (const float4*)(g_xl1 + (size_t)s * F_H + f0);
            float4 row[4];
#pragma unroll
            for (int q = 0; q < 4; ++q) row[q] = rowp[q];
            float d = 0.f;
#pragma unroll
            for (int q = 0; q < 4; ++q) {
                float z;
                z = row[q].x + xr[q].x; d = fmaf(lrelu(z), at[q].x, d);
                z = row[q].y + xr[q].y; d = fmaf(lrelu(z), at[q].y, d);
                z = row[q].z + xr[q].z; d = fmaf(lrelu(z), at[q].z, d);
                z = row[q].w + xr[q].w; d = fmaf(lrelu(z), at[q].w, d);
            }
            d += __shfl_xor(d, 1, 64);
            d += __shfl_xor(d, 2, 64);
            d += __shfl_xor(d, 4, 64);
            float e = valid ? d : -INFINITY;
            float M = e;
            M = fmaxf(M, __shfl_xor(M, 8, 64));
            M = fmaxf(M, __shfl_xor(M, 16, 64));
            M = fmaxf(M, __shfl_xor(M, 32, 64));
            float mn = fmaxf(m, M);
            float sc = __expf(m - mn);
            float p  = __expf(e - mn);
            m = mn;
            ssum = ssum * sc + p;
#pragma unroll
            for (int q = 0; q < 4; ++q) {
                acc[q].x = fmaf(p, row[q].x, acc[q].x * sc);
                acc[q].y = fmaf(p, row[q].y, acc[q].y * sc);
                acc[q].z = fmaf(p, row[q].z, acc[q].z * sc);
                acc[q].w = fmaf(p, row[q].w, acc[q].w * sc);
            }
        }
    }
#pragma unroll
    for (int off = 8; off < 64; off <<= 1) {
        ssum += __shfl_xor(ssum, off, 64);
#pragma unroll
        for (int q = 0; q < 4; ++q) {
            acc[q].x += __shfl_xor(acc[q].x, off, 64);
            acc[q].y += __shfl_xor(acc[q].y, off, 64);
            acc[q].z += __shfl_xor(acc[q].z, off, 64);
            acc[q].w += __shfl_xor(acc[q].w, off, 64);
        }
    }
    float inv = 1.f / (ssum + EPS_F);
    if (g == 0) {
        float4* op = (float4*)&s_out[wid][f0];
#pragma unroll
        for (int q = 0; q < 4; ++q) {
            float4 v;
            v.x = acc[q].x * inv; v.y = acc[q].y * inv;
            v.z = acc[q].z * inv; v.w = acc[q].w * inv;
            op[q] = v;
        }
    }
    __syncthreads();
    int f2 = lane * 2;
    float2 o = *(float2*)&s_out[wid][f2];
    o.x = fmaxf(o.x + san(bias[f2]), 0.f);
    o.y = fmaxf(o.y + san(bias[f2 + 1]), 0.f);
    unsigned short hx = f2bf(o.x), hy = f2bf(o.y);
    unsigned short lx = f2bf(o.x - bf2f(hx)), ly = f2bf(o.y - bf2f(hy));
    size_t base = (size_t)w * F_H + f2;
    *(unsigned*)(g_hh + base) = ((unsigned)hy << 16) | hx;
    *(unsigned*)(g_hl + base) = ((unsigned)ly << 16) | lx;
}

// ---------------- fused attention+aggregate, layer 2 (F=64) -----------------
__global__ __launch_bounds__(256) void att_agg2(const float* __restrict__ att,
                                                const float* __restrict__ bias,
                                                float* __restrict__ out) {
    __shared__ float s_out[4][F_OUT];
    int wid = threadIdx.x >> 6, lane = threadIdx.x & 63;
    int w = blockIdx.x * 4 + wid;
    int g = lane >> 3;
    int fi = lane & 7;
    int f0 = fi * 8;

    float4 xr[2], at[2];
    const float4* xrp = (const float4*)(g_xr2 + (size_t)w * F_OUT + f0);
    const float4* atp = (const float4*)(att + f0);
#pragma unroll
    for (int q = 0; q < 2; ++q) {
        xr[q] = xrp[q];
        float4 a = atp[q];
        a.x = san(a.x); a.y = san(a.y); a.z = san(a.z); a.w = san(a.w);
        at[q] = a;
    }

    int beg = (int)g_rowstart[w], end = (int)g_rowstart[w + 1];
    float m = -INFINITY, ssum = 0.f;
    float4 acc[2];
#pragma unroll
    for (int q = 0; q < 2; ++q) acc[q] = make_float4(0.f, 0.f, 0.f, 0.f);

    for (int c0 = beg; c0 < end; c0 += 64) {
        int nc = min(64, end - c0);
        int mysrc = (lane < nc) ? g_src_sorted[c0 + lane] : 0;
        for (int r0 = 0; r0 < nc; r0 += 8) {
            int eidx = r0 + g;
            bool valid = eidx < nc;
            int s = __shfl(mysrc, eidx, 64);
            const float4* rowp = (const float4*)(g_xl2 + (size_t)s * F_OUT + f0);
            float4 row[2];
#pragma unroll
            for (int q = 0; q < 2; ++q) row[q] = rowp[q];
            float d = 0.f;
#pragma unroll
            for (int q = 0; q < 2; ++q) {
                float z;
                z = row[q].x + xr[q].x; d = fmaf(lrelu(z), at[q].x, d);
                z = row[q].y + xr[q].y; d = fmaf(lrelu(z), at[q].y, d);
                z = row[q].z + xr[q].z; d = fmaf(lrelu(z), at[q].z, d);
                z = row[q].w + xr[q].w; d = fmaf(lrelu(z), at[q].w, d);
            }
            d += __shfl_xor(d, 1, 64);
            d += __shfl_xor(d, 2, 64);
            d += __shfl_xor(d, 4, 64);
            float e = valid ? d : -INFINITY;
            float M = e;
            M = fmaxf(M, __shfl_xor(M, 8, 64));
            M = fmaxf(M, __shfl_xor(M, 16, 64));
            M = fmaxf(M, __shfl_xor(M, 32, 64));
            float mn = fmaxf(m, M);
            float sc = __expf(m - mn);
            float p  = __expf(e - mn);
            m = mn;
            ssum = ssum * sc + p;
#pragma unroll
            for (int q = 0; q < 2; ++q) {
                acc[q].x = fmaf(p, row[q].x, acc[q].x * sc);
                acc[q].y = fmaf(p, row[q].y, acc[q].y * sc);
                acc[q].z = fmaf(p, row[q].z, acc[q].z * sc);
                acc[q].w = fmaf(p, row[q].w, acc[q].w * sc);
            }
        }
    }
#pragma unroll
    for (int off = 8; off < 64; off <<= 1) {
        ssum += __shfl_xor(ssum, off, 64);
#pragma unroll
        for (int q = 0; q < 2; ++q) {
            acc[q].x += __shfl_xor(acc[q].x, off, 64);
            acc[q].y += __shfl_xor(acc[q].y, off, 64);
            acc[q].z += __shfl_xor(acc[q].z, off, 64);
            acc[q].w += __shfl_xor(acc[q].w, off, 64);
        }
    }
    float inv = 1.f / (ssum + EPS_F);
    if (g == 0) {
        float4* op = (float4*)&s_out[wid][f0];
#pragma unroll
        for (int q = 0; q < 2; ++q) {
            float4 v;
            v.x = acc[q].x * inv; v.y = acc[q].y * inv;
            v.z = acc[q].z * inv; v.w = acc[q].w * inv;
            op[q] = v;
        }
    }
    __syncthreads();
    out[(size_t)w * F_OUT + lane] = s_out[wid][lane] + san(bias[lane]);
}

// ---------------- launch ------------------------------------------------------
extern "C" void kernel_launch(void* const* d_in, const int* in_sizes, int n_in,
                              void* d_out, int out_size, void* d_ws, size_t ws_size,
                              hipStream_t stream) {
    const float* x    = (const float*)d_in[0];
    const int*   ei   = (const int*)d_in[1];
    const float* Wl1  = (const float*)d_in[2];
    const float* Wr1  = (const float*)d_in[3];
    const float* att1 = (const float*)d_in[4];
    const float* b1   = (const float*)d_in[5];
    const float* Wl2  = (const float*)d_in[6];
    const float* Wr2  = (const float*)d_in[7];
    const float* att2 = (const float*)d_in[8];
    const float* b2   = (const float*)d_in[9];

    int E = in_sizes[1] / 2;
    const int* src = ei;
    const int* dst = ei + E;

    int gE = (E + 255) / 256;
    int gN = N_NODES / 4;
    int gSX = (M_PAD * (F_IN / 4)) / 256;
    int gSA = (E + CH_E - 1) / CH_E;

    wconv_all<<<256, 256, 0, stream>>>(Wl1, Wr1, Wl2, Wr2);
    split_x<<<gSX, 256, 0, stream>>>(x);

    // CSR by dst: hist -> scan -> two-pass locality-aware sort
    csr_zero<<<NPART, 256, 0, stream>>>();
    csr_hist<<<gE, 256, 0, stream>>>(dst, E);
    scanA<<<NPART, 256, 0, stream>>>();
    scanB<<<1, 256, 0, stream>>>(E);
    scanC<<<NPART, 256, 0, stream>>>();
    binit<<<1, 256, 0, stream>>>();
    sortA<<<gSA, 256, 0, stream>>>(src, dst, E);
    sortB<<<NBUCK, 256, 0, stream>>>();

    // ---- layer 1 ----
    gemm_mfma<1><<<dim3(MT, 2), 256, 0, stream>>>();
    att_agg1<<<gN, 256, 0, stream>>>(att1, b1);

    // ---- layer 2 ----
    pad_h<<<24, 256, 0, stream>>>();
    gemm_mfma<2><<<dim3(MT, 1), 256, 0, stream>>>();
    att_agg2<<<gN, 256, 0, stream>>>(att2, b2, (float*)d_out);
}

// Round 8
// 488.694 us; speedup vs baseline: 2.4432x; 1.1240x over previous
//
#include <hip/hip_runtime.h>

#define N_NODES 50000
#define M_PAD 50048            // 391 * 128
#define MT 391
#define F_IN 256
#define F_H 128
#define F_OUT 64
#define E_MAX 1600000
#define NEG_SLOPE 0.2f
#define EPS_F 1e-16f
#define NPART 196              // ceil(50000/256)
#define NBUCK 196              // coarse buckets: dst >> 8
#define CH_E 16384             // edges per sortA block

typedef __bf16 bf16x8 __attribute__((ext_vector_type(8)));
typedef float f32x4 __attribute__((ext_vector_type(4)));

// ---------------- device-global scratch ------------------------------------
__device__ unsigned short g_B1h[256 * 256];
__device__ unsigned short g_B1l[256 * 256];
__device__ unsigned short g_B2h[128 * 128];
__device__ unsigned short g_B2l[128 * 128];
__device__ unsigned short g_x1h[(size_t)M_PAD * F_IN];
__device__ unsigned short g_x1l[(size_t)M_PAD * F_IN];
__device__ unsigned short g_hh[(size_t)M_PAD * F_H];
__device__ unsigned short g_hl[(size_t)M_PAD * F_H];
// gather tables: xl in bf16 (halves gather bytes), xr in f32 (read once/dst)
__device__ unsigned short g_xl1b[(size_t)N_NODES * F_H];
__device__ float g_xr1[(size_t)N_NODES * F_H];
__device__ unsigned short g_xl2b[(size_t)N_NODES * F_OUT];
__device__ float g_xr2[(size_t)N_NODES * F_OUT];
// CSR by dst
__device__ unsigned g_cnt[N_NODES];
__device__ unsigned g_part[NPART];
__device__ unsigned g_rowstart[N_NODES + 1];
__device__ unsigned g_bcursor[NBUCK];
__device__ unsigned g_bucketed[E_MAX];     // packed src | dst<<16
__device__ int g_src_sorted[E_MAX];

// ---------------- helpers ---------------------------------------------------
__device__ inline float san(float v) { return fminf(fmaxf(v, -64.f), 64.f); }
__device__ inline float lrelu(float z) { return fmaxf(z, NEG_SLOPE * z); }
__device__ inline unsigned short f2bf(float f) {        // RNE f32->bf16
    unsigned u = __float_as_uint(f);
    return (unsigned short)((u + 0x7fffu + ((u >> 16) & 1u)) >> 16);
}
__device__ inline float bf2f(unsigned short h) {
    return __uint_as_float(((unsigned)h) << 16);
}
__device__ inline float blo(unsigned w) { return __uint_as_float(w << 16); }
__device__ inline float bhi(unsigned w) { return __uint_as_float(w & 0xffff0000u); }

// ---------------- weight prepack: [k][n] f32 -> [n][k] bf16 hi/lo -----------
__global__ void wconv_all(const float* __restrict__ Wl1,
                          const float* __restrict__ Wr1,
                          const float* __restrict__ Wl2,
                          const float* __restrict__ Wr2) {
    int i = blockIdx.x * blockDim.x + threadIdx.x;
    if (i < 256 * 256) {
        int n = i >> 8, k = i & 255;
        float v = san((n < 128) ? Wl1[k * 128 + n] : Wr1[k * 128 + (n - 128)]);
        unsigned short h = f2bf(v);
        g_B1h[n * 256 + k] = h;
        g_B1l[n * 256 + k] = f2bf(v - bf2f(h));
    }
    if (i < 128 * 128) {
        int n = i >> 7, k = i & 127;
        float v = san((n < 64) ? Wl2[k * 64 + n] : Wr2[k * 64 + (n - 64)]);
        unsigned short h = f2bf(v);
        g_B2h[n * 128 + k] = h;
        g_B2l[n * 128 + k] = f2bf(v - bf2f(h));
    }
}

// ---------------- x split: f32 [50000][256] -> bf16 hi/lo [50048][256] ------
__global__ void split_x(const float* __restrict__ x) {
    int i = blockIdx.x * 256 + threadIdx.x;
    int m = i >> 6, c4 = i & 63;
    float4 v = make_float4(0.f, 0.f, 0.f, 0.f);
    if (m < N_NODES) v = ((const float4*)(x + (size_t)m * F_IN))[c4];
    v.x = san(v.x); v.y = san(v.y); v.z = san(v.z); v.w = san(v.w);
    unsigned short h0 = f2bf(v.x), h1 = f2bf(v.y), h2 = f2bf(v.z), h3 = f2bf(v.w);
    unsigned short l0 = f2bf(v.x - bf2f(h0)), l1 = f2bf(v.y - bf2f(h1));
    unsigned short l2 = f2bf(v.z - bf2f(h2)), l3 = f2bf(v.w - bf2f(h3));
    size_t o = (size_t)m * F_IN + c4 * 4;
    uint2 ph = make_uint2(((unsigned)h1 << 16) | h0, ((unsigned)h3 << 16) | h2);
    uint2 pl = make_uint2(((unsigned)l1 << 16) | l0, ((unsigned)l3 << 16) | l2);
    *(uint2*)(g_x1h + o) = ph;
    *(uint2*)(g_x1l + o) = pl;
}

__global__ void pad_h() {
    int i = blockIdx.x * 256 + threadIdx.x;
    if (i < (M_PAD - N_NODES) * F_H) {
        g_hh[(size_t)N_NODES * F_H + i] = 0;
        g_hl[(size_t)N_NODES * F_H + i] = 0;
    }
}

// ---------------- CSR build --------------------------------------------------
__global__ void csr_zero() {
    int i = blockIdx.x * blockDim.x + threadIdx.x;
    if (i < N_NODES) g_cnt[i] = 0u;
}
__global__ void csr_hist(const int* __restrict__ dst, int E) {
    int e = blockIdx.x * blockDim.x + threadIdx.x;
    if (e < E) atomicAdd(&g_cnt[dst[e]], 1u);
}
__global__ __launch_bounds__(256) void scanA() {
    int i = blockIdx.x * 256 + threadIdx.x;
    unsigned v = (i < N_NODES) ? g_cnt[i] : 0u;
#pragma unroll
    for (int off = 32; off > 0; off >>= 1) v += __shfl_xor(v, off, 64);
    __shared__ unsigned ws[4];
    if ((threadIdx.x & 63) == 0) ws[threadIdx.x >> 6] = v;
    __syncthreads();
    if (threadIdx.x == 0) g_part[blockIdx.x] = ws[0] + ws[1] + ws[2] + ws[3];
}
__global__ __launch_bounds__(256) void scanB(int E) {
    __shared__ unsigned lds[256];
    int t = threadIdx.x;
    unsigned v = (t < NPART) ? g_part[t] : 0u;
    lds[t] = v;
    __syncthreads();
    for (int off = 1; off < 256; off <<= 1) {
        unsigned u = (t >= off) ? lds[t - off] : 0u;
        __syncthreads();
        lds[t] += u;
        __syncthreads();
    }
    if (t < NPART) g_part[t] = lds[t] - v;
    if (t == 0) g_rowstart[N_NODES] = (unsigned)E;
}
__global__ __launch_bounds__(256) void scanC() {
    __shared__ unsigned lds[256];
    int t = threadIdx.x;
    int i = blockIdx.x * 256 + t;
    unsigned v = (i < N_NODES) ? g_cnt[i] : 0u;
    lds[t] = v;
    __syncthreads();
    for (int off = 1; off < 256; off <<= 1) {
        unsigned u = (t >= off) ? lds[t - off] : 0u;
        __syncthreads();
        lds[t] += u;
        __syncthreads();
    }
    if (i < N_NODES) g_rowstart[i] = lds[t] - v + g_part[blockIdx.x];
}
__global__ void binit() {
    int b = blockIdx.x * 256 + threadIdx.x;
    if (b < NBUCK) g_bcursor[b] = g_rowstart[min(b * 256, N_NODES)];
}

// ---------------- two-pass locality-aware sort ------------------------------
__global__ __launch_bounds__(256) void sortA(const int* __restrict__ src,
                                             const int* __restrict__ dst, int E) {
    __shared__ unsigned l_cnt[NBUCK];
    __shared__ unsigned l_cur[NBUCK];
    __shared__ unsigned l_base[NBUCK];
    int t = threadIdx.x;
    int e0 = blockIdx.x * CH_E;
    int e1 = min(e0 + CH_E, E);
    for (int i = t; i < NBUCK; i += 256) { l_cnt[i] = 0u; l_cur[i] = 0u; }
    __syncthreads();
    for (int e = e0 + t; e < e1; e += 256)
        atomicAdd(&l_cnt[dst[e] >> 8], 1u);
    __syncthreads();
    for (int i = t; i < NBUCK; i += 256) {
        unsigned c = l_cnt[i];
        l_base[i] = c ? atomicAdd(&g_bcursor[i], c) : 0u;
    }
    __syncthreads();
    for (int e = e0 + t; e < e1; e += 256) {
        int d = dst[e];
        int b = d >> 8;
        unsigned off = atomicAdd(&l_cur[b], 1u);
        g_bucketed[l_base[b] + off] = (unsigned)src[e] | ((unsigned)d << 16);
    }
}
__global__ __launch_bounds__(256) void sortB() {
    __shared__ unsigned l_cur[256];
    int b = blockIdx.x;
    int d0 = b * 256;
    int t = threadIdx.x;
    l_cur[t] = g_rowstart[min(d0 + t, N_NODES)];
    unsigned bstart = g_rowstart[min(d0, N_NODES)];
    unsigned bend   = g_rowstart[min(d0 + 256, N_NODES)];
    __syncthreads();
    for (unsigned i = bstart + t; i < bend; i += 256) {
        unsigned e = g_bucketed[i];
        unsigned d = e >> 16;
        unsigned pos = atomicAdd(&l_cur[d - d0], 1u);
        g_src_sorted[pos] = (int)(e & 0xFFFFu);
    }
}

// ---------------- split-bf16 MFMA GEMM --------------------------------------
// Epilogue: xl columns -> bf16 table (gathered E times), xr columns -> f32.
template<int LAYER>
__global__ __launch_bounds__(256) void gemm_mfma() {
    constexpr int K    = (LAYER == 1) ? 256 : 128;
    constexpr int NSPL = (LAYER == 1) ? 128 : 64;
    const unsigned short* __restrict__ Ah = (LAYER == 1) ? g_x1h : g_hh;
    const unsigned short* __restrict__ Al = (LAYER == 1) ? g_x1l : g_hl;
    const unsigned short* __restrict__ Bh = (LAYER == 1) ? g_B1h : g_B2h;
    const unsigned short* __restrict__ Bl = (LAYER == 1) ? g_B1l : g_B2l;
    unsigned short* __restrict__ OL = (LAYER == 1) ? g_xl1b : g_xl2b;
    float* __restrict__ OR_ = (LAYER == 1) ? g_xr1 : g_xr2;

    __shared__ __align__(16) unsigned short As_h[128][40];
    __shared__ __align__(16) unsigned short As_l[128][40];
    __shared__ __align__(16) unsigned short Bs_h[128][40];
    __shared__ __align__(16) unsigned short Bs_l[128][40];

    const int m0 = blockIdx.x * 128;
    const int n0 = blockIdx.y * 128;
    const int t = threadIdx.x;
    const int wave = t >> 6, lane = t & 63;
    const int wm = (wave >> 1) * 64, wn = (wave & 1) * 64;
    const int lr = lane & 15, g8 = (lane >> 4) * 8;
    const int srow = t >> 1, shalf = (t & 1) * 16;

    f32x4 acc[4][4];
#pragma unroll
    for (int i = 0; i < 4; ++i)
#pragma unroll
        for (int j = 0; j < 4; ++j) acc[i][j] = (f32x4){0.f, 0.f, 0.f, 0.f};

    for (int kb = 0; kb < K; kb += 32) {
        __syncthreads();
        {
            size_t ga = (size_t)(m0 + srow) * K + kb + shalf;
            *(uint4*)&As_h[srow][shalf]     = *(const uint4*)(Ah + ga);
            *(uint4*)&As_h[srow][shalf + 8] = *(const uint4*)(Ah + ga + 8);
            *(uint4*)&As_l[srow][shalf]     = *(const uint4*)(Al + ga);
            *(uint4*)&As_l[srow][shalf + 8] = *(const uint4*)(Al + ga + 8);
            size_t gb = (size_t)(n0 + srow) * K + kb + shalf;
            *(uint4*)&Bs_h[srow][shalf]     = *(const uint4*)(Bh + gb);
            *(uint4*)&Bs_h[srow][shalf + 8] = *(const uint4*)(Bh + gb + 8);
            *(uint4*)&Bs_l[srow][shalf]     = *(const uint4*)(Bl + gb);
            *(uint4*)&Bs_l[srow][shalf + 8] = *(const uint4*)(Bl + gb + 8);
        }
        __syncthreads();

        bf16x8 af_h[4], af_l[4], bf_h[4], bf_l[4];
#pragma unroll
        for (int i = 0; i < 4; ++i) {
            af_h[i] = *(const bf16x8*)&As_h[wm + i * 16 + lr][g8];
            af_l[i] = *(const bf16x8*)&As_l[wm + i * 16 + lr][g8];
        }
#pragma unroll
        for (int j = 0; j < 4; ++j) {
            bf_h[j] = *(const bf16x8*)&Bs_h[wn + j * 16 + lr][g8];
            bf_l[j] = *(const bf16x8*)&Bs_l[wn + j * 16 + lr][g8];
        }
#pragma unroll
        for (int i = 0; i < 4; ++i)
#pragma unroll
            for (int j = 0; j < 4; ++j) {
                acc[i][j] = __builtin_amdgcn_mfma_f32_16x16x32_bf16(af_h[i], bf_h[j], acc[i][j], 0, 0, 0);
                acc[i][j] = __builtin_amdgcn_mfma_f32_16x16x32_bf16(af_h[i], bf_l[j], acc[i][j], 0, 0, 0);
                acc[i][j] = __builtin_amdgcn_mfma_f32_16x16x32_bf16(af_l[i], bf_h[j], acc[i][j], 0, 0, 0);
            }
    }

    const int drow = (lane >> 4) * 4;
#pragma unroll
    for (int i = 0; i < 4; ++i)
#pragma unroll
        for (int j = 0; j < 4; ++j) {
            int gn = n0 + wn + j * 16 + lr;
#pragma unroll
            for (int r = 0; r < 4; ++r) {
                int m = m0 + wm + i * 16 + drow + r;
                if (m < N_NODES) {
                    if (gn < NSPL) OL[(size_t)m * NSPL + gn] = f2bf(acc[i][j][r]);
                    else           OR_[(size_t)m * NSPL + (gn - NSPL)] = acc[i][j][r];
                }
            }
        }
}

// ---------------- fused attention+aggregate, layer 1 ------------------------
// One wave per dst. 8 edges/round x 8 lanes/edge x 16 features/lane.
// xl rows gathered as bf16 (256 B/row), unpacked in-register, reused for
// logit AND accumulate. xr/accumulation stay f32.
__global__ __launch_bounds__(256) void att_agg1(const float* __restrict__ att,
                                                const float* __restrict__ bias) {
    __shared__ float s_out[4][F_H];
    int wid = threadIdx.x >> 6, lane = threadIdx.x & 63;
    int w = blockIdx.x * 4 + wid;
    int g = lane >> 3;
    int fi = lane & 7;
    int f0 = fi * 16;

    float4 xr[4], at[4];
    const float4* xrp = (const float4*)(g_xr1 + (size_t)w * F_H + f0);
    const float4* atp = (const float4*)(att + f0);
#pragma unroll
    for (int q = 0; q < 4; ++q) {
        xr[q] = xrp[q];
        float4 a = atp[q];
        a.x = san(a.x); a.y = san(a.y); a.z = san(a.z); a.w = san(a.w);
        at[q] = a;
    }

    int beg = (int)g_rowstart[w], end = (int)g_rowstart[w + 1];
    float m = -INFINITY, ssum = 0.f;
    float4 acc[4];
#pragma unroll
    for (int q = 0; q < 4; ++q) acc[q] = make_float4(0.f, 0.f, 0.f, 0.f);

    for (int c0 = beg; c0 < end; c0 += 64) {
        int nc = min(64, end - c0);
        int mysrc = (lane < nc) ? g_src_sorted[c0 + lane] : 0;
        for (int r0 = 0; r0 < nc; r0 += 8) {
            int eidx = r0 + g;
            bool valid = eidx < nc;
            int s = __shfl(mysrc, eidx, 64);
            const uint4* rowp = (const uint4*)(g_xl1b + (size_t)s * F_H + f0);
            uint4 u0 = rowp[0], u1 = rowp[1];
            float4 row[4];
            row[0] = make_float4(blo(u0.x), bhi(u0.x), blo(u0.y), bhi(u0.y));
            row[1] = make_float4(blo(u0.z), bhi(u0.z), blo(u0.w), bhi(u0.w));
            row[2] = make_float4(blo(u1.x), bhi(u1.x), blo(u1.y), bhi(u1.y));
            row[3] = make_float4(blo(u1.z), bhi(u1.z), blo(u1.w), bhi(u1.w));
            float d = 0.f;
#pragma unroll
            for (int q = 0; q < 4; ++q) {
                float z;
                z = row[q].x + xr[q].x; d = fmaf(lrelu(z), at[q].x, d);
                z = row[q].y + xr[q].y; d = fmaf(lrelu(z), at[q].y, d);
                z = row[q].z + xr[q].z; d = fmaf(lrelu(z), at[q].z, d);
                z = row[q].w + xr[q].w; d = fmaf(lrelu(z), at[q].w, d);
            }
            d += __shfl_xor(d, 1, 64);
            d += __shfl_xor(d, 2, 64);
            d += __shfl_xor(d, 4, 64);
            float e = valid ? d : -INFINITY;
            float M = e;
            M = fmaxf(M, __shfl_xor(M, 8, 64));
            M = fmaxf(M, __shfl_xor(M, 16, 64));
            M = fmaxf(M, __shfl_xor(M, 32, 64));
            float mn = fmaxf(m, M);
            float sc = __expf(m - mn);
            float p  = __expf(e - mn);
            m = mn;
            ssum = ssum * sc + p;
#pragma unroll
            for (int q = 0; q < 4; ++q) {
                acc[q].x = fmaf(p, row[q].x, acc[q].x * sc);
                acc[q].y = fmaf(p, row[q].y, acc[q].y * sc);
                acc[q].z = fmaf(p, row[q].z, acc[q].z * sc);
                acc[q].w = fmaf(p, row[q].w, acc[q].w * sc);
            }
        }
    }
#pragma unroll
    for (int off = 8; off < 64; off <<= 1) {
        ssum += __shfl_xor(ssum, off, 64);
#pragma unroll
        for (int q = 0; q < 4; ++q) {
            acc[q].x += __shfl_xor(acc[q].x, off, 64);
            acc[q].y += __shfl_xor(acc[q].y, off, 64);
            acc[q].z += __shfl_xor(acc[q].z, off, 64);
            acc[q].w += __shfl_xor(acc[q].w, off, 64);
        }
    }
    float inv = 1.f / (ssum + EPS_F);
    if (g == 0) {
        float4* op = (float4*)&s_out[wid][f0];
#pragma unroll
        for (int q = 0; q < 4; ++q) {
            float4 v;
            v.x = acc[q].x * inv; v.y = acc[q].y * inv;
            v.z = acc[q].z * inv; v.w = acc[q].w * inv;
            op[q] = v;
        }
    }
    __syncthreads();
    int f2 = lane * 2;
    float2 o = *(float2*)&s_out[wid][f2];
    o.x = fmaxf(o.x + san(bias[f2]), 0.f);
    o.y = fmaxf(o.y + san(bias[f2 + 1]), 0.f);
    unsigned short hx = f2bf(o.x), hy = f2bf(o.y);
    unsigned short lx = f2bf(o.x - bf2f(hx)), ly = f2bf(o.y - bf2f(hy));
    size_t base = (size_t)w * F_H + f2;
    *(unsigned*)(g_hh + base) = ((unsigned)hy << 16) | hx;
    *(unsigned*)(g_hl + base) = ((unsigned)ly << 16) | lx;
}

// ---------------- fused attention+aggregate, layer 2 (F=64) -----------------
__global__ __launch_bounds__(256) void att_agg2(const float* __restrict__ att,
                                                const float* __restrict__ bias,
                                                float* __restrict__ out) {
    __shared__ float s_out[4][F_OUT];
    int wid = threadIdx.x >> 6, lane = threadIdx.x & 63;
    int w = blockIdx.x * 4 + wid;
    int g = lane >> 3;
    int fi = lane & 7;
    int f0 = fi * 8;

    float4 xr[2], at[2];
    const float4* xrp = (const float4*)(g_xr2 + (size_t)w * F_OUT + f0);
    const float4* atp = (const float4*)(att + f0);
#pragma unroll
    for (int q = 0; q < 2; ++q) {
        xr[q] = xrp[q];
        float4 a = atp[q];
        a.x = san(a.x); a.y = san(a.y); a.z = san(a.z); a.w = san(a.w);
        at[q] = a;
    }

    int beg = (int)g_rowstart[w], end = (int)g_rowstart[w + 1];
    float m = -INFINITY, ssum = 0.f;
    float4 acc[2];
#pragma unroll
    for (int q = 0; q < 2; ++q) acc[q] = make_float4(0.f, 0.f, 0.f, 0.f);

    for (int c0 = beg; c0 < end; c0 += 64) {
        int nc = min(64, end - c0);
        int mysrc = (lane < nc) ? g_src_sorted[c0 + lane] : 0;
        for (int r0 = 0; r0 < nc; r0 += 8) {
            int eidx = r0 + g;
            bool valid = eidx < nc;
            int s = __shfl(mysrc, eidx, 64);
            uint4 u0 = *(const uint4*)(g_xl2b + (size_t)s * F_OUT + f0);
            float4 row[2];
            row[0] = make_float4(blo(u0.x), bhi(u0.x), blo(u0.y), bhi(u0.y));
            row[1] = make_float4(blo(u0.z), bhi(u0.z), blo(u0.w), bhi(u0.w));
            float d = 0.f;
#pragma unroll
            for (int q = 0; q < 2; ++q) {
                float z;
                z = row[q].x + xr[q].x; d = fmaf(lrelu(z), at[q].x, d);
                z = row[q].y + xr[q].y; d = fmaf(lrelu(z), at[q].y, d);
                z = row[q].z + xr[q].z; d = fmaf(lrelu(z), at[q].z, d);
                z = row[q].w + xr[q].w; d = fmaf(lrelu(z), at[q].w, d);
            }
            d += __shfl_xor(d, 1, 64);
            d += __shfl_xor(d, 2, 64);
            d += __shfl_xor(d, 4, 64);
            float e = valid ? d : -INFINITY;
            float M = e;
            M = fmaxf(M, __shfl_xor(M, 8, 64));
            M = fmaxf(M, __shfl_xor(M, 16, 64));
            M = fmaxf(M, __shfl_xor(M, 32, 64));
            float mn = fmaxf(m, M);
            float sc = __expf(m - mn);
            float p  = __expf(e - mn);
            m = mn;
            ssum = ssum * sc + p;
#pragma unroll
            for (int q = 0; q < 2; ++q) {
                acc[q].x = fmaf(p, row[q].x, acc[q].x * sc);
                acc[q].y = fmaf(p, row[q].y, acc[q].y * sc);
                acc[q].z = fmaf(p, row[q].z, acc[q].z * sc);
                acc[q].w = fmaf(p, row[q].w, acc[q].w * sc);
            }
        }
    }
#pragma unroll
    for (int off = 8; off < 64; off <<= 1) {
        ssum += __shfl_xor(ssum, off, 64);
#pragma unroll
        for (int q = 0; q < 2; ++q) {
            acc[q].x += __shfl_xor(acc[q].x, off, 64);
            acc[q].y += __shfl_xor(acc[q].y, off, 64);
            acc[q].z += __shfl_xor(acc[q].z, off, 64);
            acc[q].w += __shfl_xor(acc[q].w, off, 64);
        }
    }
    float inv = 1.f / (ssum + EPS_F);
    if (g == 0) {
        float4* op = (float4*)&s_out[wid][f0];
#pragma unroll
        for (int q = 0; q < 2; ++q) {
            float4 v;
            v.x = acc[q].x * inv; v.y = acc[q].y * inv;
            v.z = acc[q].z * inv; v.w = acc[q].w * inv;
            op[q] = v;
        }
    }
    __syncthreads();
    out[(size_t)w * F_OUT + lane] = s_out[wid][lane] + san(bias[lane]);
}

// ---------------- launch ------------------------------------------------------
extern "C" void kernel_launch(void* const* d_in, const int* in_sizes, int n_in,
                              void* d_out, int out_size, void* d_ws, size_t ws_size,
                              hipStream_t stream) {
    const float* x    = (const float*)d_in[0];
    const int*   ei   = (const int*)d_in[1];
    const float* Wl1  = (const float*)d_in[2];
    const float* Wr1  = (const float*)d_in[3];
    const float* att1 = (const float*)d_in[4];
    const float* b1   = (const float*)d_in[5];
    const float* Wl2  = (const float*)d_in[6];
    const float* Wr2  = (const float*)d_in[7];
    const float* att2 = (const float*)d_in[8];
    const float* b2   = (const float*)d_in[9];

    int E = in_sizes[1] / 2;
    const int* src = ei;
    const int* dst = ei + E;

    int gE = (E + 255) / 256;
    int gN = N_NODES / 4;
    int gSX = (M_PAD * (F_IN / 4)) / 256;
    int gSA = (E + CH_E - 1) / CH_E;

    wconv_all<<<256, 256, 0, stream>>>(Wl1, Wr1, Wl2, Wr2);
    split_x<<<gSX, 256, 0, stream>>>(x);

    // CSR by dst: hist -> scan -> two-pass locality-aware sort
    csr_zero<<<NPART, 256, 0, stream>>>();
    csr_hist<<<gE, 256, 0, stream>>>(dst, E);
    scanA<<<NPART, 256, 0, stream>>>();
    scanB<<<1, 256, 0, stream>>>(E);
    scanC<<<NPART, 256, 0, stream>>>();
    binit<<<1, 256, 0, stream>>>();
    sortA<<<gSA, 256, 0, stream>>>(src, dst, E);
    sortB<<<NBUCK, 256, 0, stream>>>();

    // ---- layer 1 ----
    gemm_mfma<1><<<dim3(MT, 2), 256, 0, stream>>>();
    att_agg1<<<gN, 256, 0, stream>>>(att1, b1);

    // ---- layer 2 ----
    pad_h<<<24, 256, 0, stream>>>();
    gemm_mfma<2><<<dim3(MT, 1), 256, 0, stream>>>();
    att_agg2<<<gN, 256, 0, stream>>>(att2, b2, (float*)d_out);
}